// Round 2
// baseline (453.751 us; speedup 1.0000x reference)
//
#include <hip/hip_runtime.h>
#include <math.h>

#define HW 65536
#define WD 256
#define HT 256

typedef short short8 __attribute__((ext_vector_type(8)));
typedef float f32x4 __attribute__((ext_vector_type(4)));
typedef __bf16 bf16x8 __attribute__((ext_vector_type(8)));

__device__ __forceinline__ short f2bf(float f) {
    union { float f; unsigned u; } v; v.f = f;
    unsigned r = (v.u + 0x7fffu + ((v.u >> 16) & 1u)) >> 16;
    return (short)r;
}

__device__ __forceinline__ float bf2f(short s) {
    union { unsigned u; float f; } v;
    v.u = ((unsigned)(unsigned short)s) << 16;
    return v.f;
}

__device__ __forceinline__ int iclamp(int v, int lo, int hi) {
    return v < lo ? lo : (v > hi ? hi : v);
}

struct Taps {
    int i00, i01, i10, i11;
    float w00, w01, w10, w11;
};

__device__ __forceinline__ Taps make_taps(float py, float px) {
    float fy0 = floorf(py), fx0 = floorf(px);
    float wy = py - fy0, wx = px - fx0;
    int y0 = (int)fy0, x0 = (int)fx0;
    int y1 = y0 + 1, x1 = x0 + 1;
    float vy0 = (y0 >= 0 && y0 <= HT - 1) ? 1.f : 0.f;
    float vy1 = (y1 >= 0 && y1 <= HT - 1) ? 1.f : 0.f;
    float vx0 = (x0 >= 0 && x0 <= WD - 1) ? 1.f : 0.f;
    float vx1 = (x1 >= 0 && x1 <= WD - 1) ? 1.f : 0.f;
    int yc0 = iclamp(y0, 0, HT - 1), yc1 = iclamp(y1, 0, HT - 1);
    int xc0 = iclamp(x0, 0, WD - 1), xc1 = iclamp(x1, 0, WD - 1);
    Taps t;
    t.i00 = yc0 * WD + xc0; t.i01 = yc0 * WD + xc1;
    t.i10 = yc1 * WD + xc0; t.i11 = yc1 * WD + xc1;
    t.w00 = (1.f - wy) * (1.f - wx) * vy0 * vx0;
    t.w01 = (1.f - wy) * wx * vy0 * vx1;
    t.w10 = wy * (1.f - wx) * vy1 * vx0;
    t.w11 = wy * wx * vy1 * vx1;
    return t;
}

// ---------------------------------------------------------------------------
// pack_x1: warp(nbr) + ref -> X1 (B,HW,128) NHWC bf16, via LDS transpose.
// ---------------------------------------------------------------------------
__global__ __launch_bounds__(256) void pack_x1_kernel(
    const float* __restrict__ nbr, const float* __restrict__ ref,
    const float* __restrict__ flow, short* __restrict__ X1)
{
    __shared__ short tile[64 * 130];
    int blk = blockIdx.x;              // b*1024 + grp
    int b = blk >> 10;
    int grp = blk & 1023;
    int px = threadIdx.x & 63;
    int qq = threadIdx.x >> 6;
    int pos = grp * 64 + px;
    int yy = pos >> 8, xx = pos & 255;

    float fx = flow[b * 2 * HW + pos];
    float fy = flow[b * 2 * HW + HW + pos];
    Taps tp = make_taps((float)yy + fy, (float)xx + fx);

    const float* nb = nbr + (size_t)b * 64 * HW;
    const float* rf = ref + (size_t)b * 64 * HW;
    #pragma unroll
    for (int j = 0; j < 16; ++j) {
        int c = qq * 16 + j;
        const float* pc = nb + c * HW;
        float v = tp.w00 * pc[tp.i00] + tp.w01 * pc[tp.i01] +
                  tp.w10 * pc[tp.i10] + tp.w11 * pc[tp.i11];
        tile[px * 130 + c] = f2bf(v);
        tile[px * 130 + 64 + c] = f2bf(rf[c * HW + pos]);
    }
    __syncthreads();

    short* xo = X1 + ((size_t)b * HW + grp * 64) * 128;
    #pragma unroll
    for (int f8 = threadIdx.x; f8 < 1024; f8 += 256) {
        int p = (f8 * 8) >> 7;
        int c = (f8 * 8) & 127;
        short8 v;
        #pragma unroll
        for (int j = 0; j < 8; ++j) v[j] = tile[p * 130 + c + j];
        *(short8*)(xo + f8 * 8) = v;
    }
}

// ---------------------------------------------------------------------------
// pack_nbr: nbr (B,64,HW) f32 -> N2 (B,HW,64) bf16 via LDS transpose.
// ---------------------------------------------------------------------------
__global__ __launch_bounds__(256) void pack_nbr_kernel(
    const float* __restrict__ nbr, short* __restrict__ N2)
{
    __shared__ short tile[64 * 66];
    int blk = blockIdx.x;              // b*1024 + grp
    int b = blk >> 10;
    int grp = blk & 1023;
    int px = threadIdx.x & 63;
    int qq = threadIdx.x >> 6;
    int pos = grp * 64 + px;

    const float* nb = nbr + (size_t)b * 64 * HW;
    #pragma unroll
    for (int j = 0; j < 16; ++j) {
        int c = qq * 16 + j;
        tile[px * 66 + c] = f2bf(nb[c * HW + pos]);
    }
    __syncthreads();

    short* xo = N2 + ((size_t)b * HW + grp * 64) * 64;
    #pragma unroll
    for (int f8 = threadIdx.x; f8 < 512; f8 += 256) {
        int p = f8 >> 3;
        int c = (f8 & 7) * 8;
        short8 v;
        #pragma unroll
        for (int j = 0; j < 8; ++j) v[j] = tile[p * 66 + c + j];
        *(short8*)(xo + f8 * 8) = v;
    }
}

// ---------------------------------------------------------------------------
// pack_x2_flow: fill X2 channels 64..95 (flow bf16 + zero pad).
// ---------------------------------------------------------------------------
__global__ __launch_bounds__(256) void pack_x2_flow_kernel(
    const float* __restrict__ flow, short* __restrict__ X2)
{
    int t = blockIdx.x * 256 + threadIdx.x;   // 2*HW
    int b = t >> 16;
    int pos = t & (HW - 1);
    short bx = f2bf(flow[b * 2 * HW + pos]);
    short by = f2bf(flow[b * 2 * HW + HW + pos]);
    short* p = X2 + ((size_t)b * HW + pos) * 96 + 64;
    short8 first = {bx, by, 0, 0, 0, 0, 0, 0};
    short8 z = {0, 0, 0, 0, 0, 0, 0, 0};
    *(short8*)(p) = first;
    *(short8*)(p + 8) = z;
    *(short8*)(p + 16) = z;
    *(short8*)(p + 24) = z;
}

// ---------------------------------------------------------------------------
// Weight repacks to MFMA B-fragment order.
// ---------------------------------------------------------------------------
__global__ __launch_bounds__(256) void repack_w1_kernel(
    const float* __restrict__ w, short* __restrict__ wr)
{
    int t = blockIdx.x * 256 + threadIdx.x;  // 73728
    int j = t & 7, q = (t >> 3) & 3, l = (t >> 5) & 15;
    int nt = (t >> 9) & 3, kc = t >> 11;
    int k = kc * 32 + q * 8 + j;
    int rs = k >> 7, c = k & 127;
    int n = nt * 16 + l;
    wr[t] = f2bf(w[(n * 128 + c) * 9 + rs]);
}

__global__ __launch_bounds__(256) void repack_w2_kernel(
    const float* __restrict__ w, short* __restrict__ wr)
{
    int t = blockIdx.x * 256 + threadIdx.x;  // 221184
    int j = t & 7, q = (t >> 3) & 3, l = (t >> 5) & 15;
    int nt = (t >> 9) & 15, kc = t >> 13;
    int k = kc * 32 + q * 8 + j;
    int rs = k / 96, c = k % 96;
    int n = nt * 16 + l;
    float v = (n < 216 && c < 66) ? w[(n * 66 + c) * 9 + rs] : 0.f;
    wr[t] = f2bf(v);
}

// dcn weights -> B-frag order: flat = (((g*3+kc)*4+nt)*64 + l15*4+q)*8 + j
__global__ __launch_bounds__(256) void repack_dcn_kernel(
    const float* __restrict__ w, short* __restrict__ wr)
{
    int t = blockIdx.x * 256 + threadIdx.x;   // 49152
    int j = t & 7, q = (t >> 3) & 3, l = (t >> 5) & 15;
    int rem = t >> 9;           // (g*3+kc)*4 + nt
    int nt = rem & 3;
    int gkc = rem >> 2;         // g*3 + kc
    int kc = gkc % 3, g = gkc / 3;
    int Kidx = kc * 32 + q * 8 + j;
    int k = Kidx >> 3, c = Kidx & 7;
    int och = nt * 16 + l;
    float v = (k < 9) ? w[(och * 64 + g * 8 + c) * 9 + k] : 0.f;
    wr[t] = f2bf(v);
}

// ---------------------------------------------------------------------------
// conv1 MFMA: X1 (NHWC bf16, 128ch) -> fea ch 0..63 of X2 (NHWC bf16, 96).
// ---------------------------------------------------------------------------
#define PADC1 136
__global__ __launch_bounds__(256) void conv1_mfma_kernel(
    const short* __restrict__ X1, const float* __restrict__ bias,
    const short* __restrict__ wr, short* __restrict__ X2)
{
    __shared__ short lds[3 * 66 * PADC1];
    const int tid = threadIdx.x;
    const int w = __builtin_amdgcn_readfirstlane(tid >> 6);
    const int l15 = tid & 15;
    const int q = (tid >> 4) & 3;
    const int blk = ((blockIdx.x & 7) << 8) | (blockIdx.x >> 3);  // XCD swizzle (2048 % 8 == 0)
    const int xseg = blk & 3;
    const int yy = (blk >> 2) & 255;
    const int b = blk >> 10;
    const int x0 = xseg * 64;

    const short* xin = X1 + (size_t)b * HW * 128;
    for (int i = tid; i < 198 * 16; i += 256) {
        int c16 = i & 15;
        int pix = i >> 4;
        int r = pix / 66, xx = pix % 66;
        int gy = yy + r - 1, gx = x0 + xx - 1;
        short8 v = {0, 0, 0, 0, 0, 0, 0, 0};
        if (gy >= 0 && gy < HT && gx >= 0 && gx < WD)
            v = *(const short8*)(xin + ((size_t)((gy << 8) + gx)) * 128 + c16 * 8);
        *(short8*)(&lds[(r * 66 + xx) * PADC1 + c16 * 8]) = v;
    }
    __syncthreads();

    f32x4 acc[4] = {{0,0,0,0},{0,0,0,0},{0,0,0,0},{0,0,0,0}};
    const int bbase = l15 * 4 + q;
    const int abase = l15 * PADC1 + q * 8;

    #define LOADB1(kc_) (*(const short8*)(wr + ((size_t)(((kc_) * 4 + w) * 64 + bbase)) * 8))
    #define COMP1(kc_, bf_) { \
        int rs_ = (kc_) >> 2, cc_ = (kc_) & 3; \
        int r_ = rs_ / 3, s_ = rs_ % 3; \
        int ao_ = (r_ * 66 + s_) * PADC1 + cc_ * 32 + abase; \
        _Pragma("unroll") \
        for (int mt = 0; mt < 4; ++mt) { \
            short8 a_ = *(const short8*)(&lds[ao_ + mt * 16 * PADC1]); \
            acc[mt] = __builtin_amdgcn_mfma_f32_16x16x32_bf16(a_, bf_, acc[mt], 0, 0, 0); \
        } }

    short8 bA = LOADB1(0), bB;
    #pragma unroll 1
    for (int jj = 0; jj < 18; ++jj) {
        int kc0 = 2 * jj;
        bB = LOADB1(kc0 + 1);
        COMP1(kc0, bA);
        int kc2 = kc0 + 2; if (kc2 > 35) kc2 = 35;
        bA = LOADB1(kc2);
        COMP1(kc0 + 1, bB);
    }
    #undef LOADB1
    #undef COMP1

    float bv = bias[w * 16 + l15];
    short* xo = X2 + (size_t)b * HW * 96;
    #pragma unroll
    for (int mt = 0; mt < 4; ++mt) {
        #pragma unroll
        for (int rg = 0; rg < 4; ++rg) {
            int px = x0 + mt * 16 + q * 4 + rg;
            float v = fmaxf(acc[mt][rg] + bv, 0.f);
            xo[((size_t)((yy << 8) + px)) * 96 + w * 16 + l15] = f2bf(v);
        }
    }
}

// ---------------------------------------------------------------------------
// om MFMA: X2 (NHWC bf16, 96ch) -> omraw (B,216,HW) fp32. XCD-swizzled.
// ---------------------------------------------------------------------------
#define PADC2 104
__global__ __launch_bounds__(256) void om_mfma_kernel(
    const short* __restrict__ X2, const short* __restrict__ wr,
    const float* __restrict__ bias, float* __restrict__ omraw)
{
    __shared__ short lds[3 * 66 * PADC2];
    const int tid = threadIdx.x;
    const int w = __builtin_amdgcn_readfirstlane(tid >> 6);
    const int l15 = tid & 15;
    const int q = (tid >> 4) & 3;
    const int blk = ((blockIdx.x & 7) << 8) | (blockIdx.x >> 3);  // XCD swizzle
    const int xseg = blk & 3;
    const int yy = (blk >> 2) & 255;
    const int b = blk >> 10;
    const int x0 = xseg * 64;

    const short* xin = X2 + (size_t)b * HW * 96;
    for (int i = tid; i < 198 * 12; i += 256) {
        int pix = i / 12;
        int c8 = i - pix * 12;
        int r = pix / 66, xx = pix % 66;
        int gy = yy + r - 1, gx = x0 + xx - 1;
        short8 v = {0, 0, 0, 0, 0, 0, 0, 0};
        if (gy >= 0 && gy < HT && gx >= 0 && gx < WD)
            v = *(const short8*)(xin + ((size_t)((gy << 8) + gx)) * 96 + c8 * 8);
        *(short8*)(&lds[(r * 66 + xx) * PADC2 + c8 * 8]) = v;
    }
    __syncthreads();

    f32x4 acc[4][4];
    #pragma unroll
    for (int i = 0; i < 4; ++i)
        #pragma unroll
        for (int mt = 0; mt < 4; ++mt) acc[i][mt] = (f32x4){0,0,0,0};

    const int bbase = l15 * 4 + q;
    const int abase = l15 * PADC2 + q * 8;

    #define LOADB2(dst_, kc_) { \
        _Pragma("unroll") \
        for (int i = 0; i < 4; ++i) \
            dst_[i] = *(const short8*)(wr + ((size_t)(((kc_) * 16 + w * 4 + i) * 64 + bbase)) * 8); }
    #define COMP2(kc_, bf_) { \
        int r_ = (kc_) / 9, s_ = ((kc_) / 3) % 3, cc_ = (kc_) % 3; \
        int ao_ = (r_ * 66 + s_) * PADC2 + cc_ * 32 + abase; \
        short8 a_[4]; \
        _Pragma("unroll") \
        for (int mt = 0; mt < 4; ++mt) \
            a_[mt] = *(const short8*)(&lds[ao_ + mt * 16 * PADC2]); \
        _Pragma("unroll") \
        for (int i = 0; i < 4; ++i) \
            _Pragma("unroll") \
            for (int mt = 0; mt < 4; ++mt) \
                acc[i][mt] = __builtin_amdgcn_mfma_f32_16x16x32_bf16(a_[mt], bf_[i], acc[i][mt], 0, 0, 0); }

    short8 bA[4], bB[4];
    LOADB2(bA, 0);
    #pragma unroll 1
    for (int jj = 0; jj < 13; ++jj) {
        int kc0 = 2 * jj;
        LOADB2(bB, kc0 + 1);
        COMP2(kc0, bA);
        LOADB2(bA, kc0 + 2);
        COMP2(kc0 + 1, bB);
    }
    COMP2(26, bA);
    #undef LOADB2
    #undef COMP2

    float* ldsT = (float*)lds;
    const int LT = 67;
    #pragma unroll 1
    for (int pass = 0; pass < 2; ++pass) {
        __syncthreads();
        if ((w >> 1) == pass) {
            int wl = w & 1;
            #pragma unroll
            for (int i = 0; i < 4; ++i) {
                int chl = (wl * 4 + i) * 16 + l15;
                #pragma unroll
                for (int mt = 0; mt < 4; ++mt)
                    #pragma unroll
                    for (int rg = 0; rg < 4; ++rg)
                        ldsT[chl * LT + mt * 16 + q * 4 + rg] = acc[i][mt][rg];
            }
        }
        __syncthreads();
        int chbase = pass * 128;
        for (int f = tid; f < 128 * 64; f += 256) {
            int chl = f >> 6, px = f & 63;
            int ch = chbase + chl;
            if (ch < 216) {
                float v = ldsT[chl * LT + px] + bias[ch];
                omraw[((size_t)b * 216 + ch) * HW + (yy << 8) + x0 + px] = v;
            }
        }
    }
}

// ---------------------------------------------------------------------------
// dcn MFMA — wave-independent restructure (barrier-free main loop).
// Each of the 4 waves owns 2 complete deformable groups: it loads that
// group's raw offsets/mask (lane = pixel, 27 scalars), computes all 9 taps
// (36 gathers in flight), blends into a WAVE-PRIVATE LDS A-tile (13.3 KB),
// and runs the full MFMA chunk itself, accumulating all 64 out-channels
// (acc[4][4]). Same-wave LDS ops are pipeline-ordered -> no __syncthreads
// in the main loop; the CU scheduler interleaves independent waves to hide
// gather latency. A 5-barrier LDS reduction sums the 4 partial accumulators.
// ---------------------------------------------------------------------------
__global__ __launch_bounds__(256, 3) void dcn_mfma_kernel(
    const float* __restrict__ raw,    // (B,216,HW)
    const float* __restrict__ flow,   // (B,2,HW)
    const short* __restrict__ N2,     // (B,HW,64) bf16
    const short* __restrict__ wrd,    // B-frag order, 49152
    const float* __restrict__ bias,   // 64
    float* __restrict__ out)          // (B,64,HW)
{
    __shared__ __align__(16) char ldsraw[53248];
    const int tid = threadIdx.x;
    const int w = __builtin_amdgcn_readfirstlane(tid >> 6);
    const int l15 = tid & 15;
    const int q = (tid >> 4) & 3;
    const int px = tid & 63;

    short* ldsA = (short*)(ldsraw + w * 13312);   // wave-private [64 px][104]
    float* ldsT = (float*)ldsraw;                  // [64 och][68] epilogue alias

    const int blk = ((blockIdx.x & 7) << 8) | (blockIdx.x >> 3);  // XCD swizzle
    const int b = blk >> 10;
    const int grp = blk & 1023;
    const int pos0 = grp * 64;
    const int pos = pos0 + px;
    const int yy = pos >> 8, xx = pos & 255;

    const float* rawb = raw + (size_t)b * 216 * HW + pos;
    const float fx = flow[b * 2 * HW + pos];
    const float fy = flow[b * 2 * HW + HW + pos];
    const short* nb2 = N2 + (size_t)b * HW * 64;

    // zero pad K-slots (taps 9..11) once; never written again
    {
        short8 z = {0, 0, 0, 0, 0, 0, 0, 0};
        *(short8*)(&ldsA[px * 104 + 72]) = z;
        *(short8*)(&ldsA[px * 104 + 80]) = z;
        *(short8*)(&ldsA[px * 104 + 88]) = z;
    }

    f32x4 acc[4][4];
    #pragma unroll
    for (int ot = 0; ot < 4; ++ot)
        #pragma unroll
        for (int mt = 0; mt < 4; ++mt) acc[ot][mt] = (f32x4){0, 0, 0, 0};

    #pragma unroll 1
    for (int i = 0; i < 2; ++i) {
        const int g = w * 2 + i;
        const float* rgp = rawb + (size_t)(g * 18) * HW;
        const float* rmp = rawb + (size_t)(144 + g * 9) * HW;
        const short* nbg = nb2 + g * 8;

        // fill the wave-private A-tile: 9 taps, lane = pixel
        #pragma unroll
        for (int t = 0; t < 9; ++t) {
            float dy = rgp[(size_t)(2 * t) * HW] + fy;
            float dx = rgp[(size_t)(2 * t + 1) * HW] + fx;
            float mr = rmp[(size_t)t * HW];
            float m = 1.f / (1.f + __expf(-mr));
            float py  = (float)(yy - 1 + t / 3) + dy;
            float pxx = (float)(xx - 1 + t % 3) + dx;
            Taps tp = make_taps(py, pxx);
            float w00 = tp.w00 * m, w01 = tp.w01 * m;
            float w10 = tp.w10 * m, w11 = tp.w11 * m;
            short8 a00 = *(const short8*)(nbg + (size_t)tp.i00 * 64);
            short8 a01 = *(const short8*)(nbg + (size_t)tp.i01 * 64);
            short8 a10 = *(const short8*)(nbg + (size_t)tp.i10 * 64);
            short8 a11 = *(const short8*)(nbg + (size_t)tp.i11 * 64);
            union { bf16x8 bv; short8 s; } u;
            #pragma unroll
            for (int c = 0; c < 8; ++c) {
                float s = w00 * bf2f(a00[c]) + w01 * bf2f(a01[c]) +
                          w10 * bf2f(a10[c]) + w11 * bf2f(a11[c]);
                u.bv[c] = (__bf16)s;
            }
            *(short8*)(&ldsA[px * 104 + t * 8]) = u.s;
        }

        // MFMA: K = 96 (3 chunks), this wave computes ALL 4 och-tiles.
        // Same-wave ds_read after ds_write is pipeline-ordered: no barrier.
        #pragma unroll
        for (int kc = 0; kc < 3; ++kc) {
            short8 bf[4];
            #pragma unroll
            for (int ot = 0; ot < 4; ++ot)
                bf[ot] = *(const short8*)(wrd +
                    ((size_t)(((g * 3 + kc) * 4 + ot) * 64 + l15 * 4 + q)) * 8);
            #pragma unroll
            for (int mt = 0; mt < 4; ++mt) {
                short8 a = *(const short8*)(&ldsA[(mt * 16 + l15) * 104 + kc * 32 + q * 8]);
                #pragma unroll
                for (int ot = 0; ot < 4; ++ot)
                    acc[ot][mt] = __builtin_amdgcn_mfma_f32_16x16x32_bf16(
                        a, bf[ot], acc[ot][mt], 0, 0, 0);
            }
        }
    }

    // epilogue: cross-wave reduction in LDS (stride 68 floats -> 16B-aligned
    // f32x4 rows), then coalesced NCHW stores (+bias).
    __syncthreads();
    #pragma unroll 1
    for (int wv = 0; wv < 4; ++wv) {
        if (w == wv) {
            #pragma unroll
            for (int ot = 0; ot < 4; ++ot)
                #pragma unroll
                for (int mt = 0; mt < 4; ++mt) {
                    f32x4* p = (f32x4*)(&ldsT[(ot * 16 + l15) * 68 + mt * 16 + q * 4]);
                    if (wv == 0) *p = acc[ot][mt];
                    else { f32x4 v = *p; v += acc[ot][mt]; *p = v; }
                }
        }
        __syncthreads();
    }
    float* ob = out + (size_t)b * 64 * HW + pos0;
    for (int f = tid; f < 4096; f += 256) {
        int och = f >> 6, p2 = f & 63;
        ob[(size_t)och * HW + p2] = ldsT[och * 68 + p2] + bias[och];
    }
}

// ---------------------------------------------------------------------------
extern "C" void kernel_launch(void* const* d_in, const int* in_sizes, int n_in,
                              void* d_out, int out_size, void* d_ws, size_t ws_size,
                              hipStream_t stream)
{
    const float* nbr  = (const float*)d_in[0];
    const float* ref  = (const float*)d_in[1];
    const float* flow = (const float*)d_in[2];
    const float* c1w  = (const float*)d_in[3];
    const float* c1b  = (const float*)d_in[4];
    const float* omw  = (const float*)d_in[5];
    const float* omb  = (const float*)d_in[6];
    const float* dw   = (const float*)d_in[7];
    const float* db   = (const float*)d_in[8];
    float* out = (float*)d_out;

    char* wsb = (char*)d_ws;
    short* X1    = (short*)(wsb);                  // 33,554,432 B
    short* X2    = (short*)(wsb + 33554432);       // 25,165,824 B
    float* omraw = (float*)(wsb + 58720256);       // 113,246,208 B
    short* wr1   = (short*)(wsb + 171966464);      // 147,456 B
    short* wr2   = (short*)(wsb + 172113920);      // 442,368 B
    short* wrd   = (short*)(wsb + 172556288);      // 98,304 B
    // N2 aliases X1: X1 is dead after conv1_mfma; stream serializes kernels.
    short* N2    = X1;                             // 16,777,216 B

    repack_w1_kernel<<<288, 256, 0, stream>>>(c1w, wr1);
    repack_w2_kernel<<<864, 256, 0, stream>>>(omw, wr2);
    repack_dcn_kernel<<<192, 256, 0, stream>>>(dw, wrd);
    pack_x1_kernel<<<2048, 256, 0, stream>>>(nbr, ref, flow, X1);
    pack_x2_flow_kernel<<<512, 256, 0, stream>>>(flow, X2);
    conv1_mfma_kernel<<<2048, 256, 0, stream>>>(X1, c1b, wr1, X2);
    pack_nbr_kernel<<<2048, 256, 0, stream>>>(nbr, N2);   // overwrites X1
    om_mfma_kernel<<<2048, 256, 0, stream>>>(X2, wr2, omb, omraw);
    dcn_mfma_kernel<<<2048, 256, 0, stream>>>(omraw, flow, N2, wrd, db, out);
}

// Round 3
// 440.390 us; speedup vs baseline: 1.0303x; 1.0303x over previous
//
#include <hip/hip_runtime.h>
#include <math.h>

#define HW 65536
#define WD 256
#define HT 256

typedef short short8 __attribute__((ext_vector_type(8)));
typedef float f32x4 __attribute__((ext_vector_type(4)));
typedef __bf16 bf16x8 __attribute__((ext_vector_type(8)));

__device__ __forceinline__ short f2bf(float f) {
    union { float f; unsigned u; } v; v.f = f;
    unsigned r = (v.u + 0x7fffu + ((v.u >> 16) & 1u)) >> 16;
    return (short)r;
}

__device__ __forceinline__ float bf2f(short s) {
    union { unsigned u; float f; } v;
    v.u = ((unsigned)(unsigned short)s) << 16;
    return v.f;
}

__device__ __forceinline__ int iclamp(int v, int lo, int hi) {
    return v < lo ? lo : (v > hi ? hi : v);
}

struct Taps {
    int i00, i01, i10, i11;
    float w00, w01, w10, w11;
};

__device__ __forceinline__ Taps make_taps(float py, float px) {
    float fy0 = floorf(py), fx0 = floorf(px);
    float wy = py - fy0, wx = px - fx0;
    int y0 = (int)fy0, x0 = (int)fx0;
    int y1 = y0 + 1, x1 = x0 + 1;
    float vy0 = (y0 >= 0 && y0 <= HT - 1) ? 1.f : 0.f;
    float vy1 = (y1 >= 0 && y1 <= HT - 1) ? 1.f : 0.f;
    float vx0 = (x0 >= 0 && x0 <= WD - 1) ? 1.f : 0.f;
    float vx1 = (x1 >= 0 && x1 <= WD - 1) ? 1.f : 0.f;
    int yc0 = iclamp(y0, 0, HT - 1), yc1 = iclamp(y1, 0, HT - 1);
    int xc0 = iclamp(x0, 0, WD - 1), xc1 = iclamp(x1, 0, WD - 1);
    Taps t;
    t.i00 = yc0 * WD + xc0; t.i01 = yc0 * WD + xc1;
    t.i10 = yc1 * WD + xc0; t.i11 = yc1 * WD + xc1;
    t.w00 = (1.f - wy) * (1.f - wx) * vy0 * vx0;
    t.w01 = (1.f - wy) * wx * vy0 * vx1;
    t.w10 = wy * (1.f - wx) * vy1 * vx0;
    t.w11 = wy * wx * vy1 * vx1;
    return t;
}

// ---------------------------------------------------------------------------
// pack_x1: warp(nbr) + ref -> X1 (B,HW,128) NHWC bf16, via LDS transpose.
// ---------------------------------------------------------------------------
__global__ __launch_bounds__(256) void pack_x1_kernel(
    const float* __restrict__ nbr, const float* __restrict__ ref,
    const float* __restrict__ flow, short* __restrict__ X1)
{
    __shared__ short tile[64 * 130];
    int blk = blockIdx.x;              // b*1024 + grp
    int b = blk >> 10;
    int grp = blk & 1023;
    int px = threadIdx.x & 63;
    int qq = threadIdx.x >> 6;
    int pos = grp * 64 + px;
    int yy = pos >> 8, xx = pos & 255;

    float fx = flow[b * 2 * HW + pos];
    float fy = flow[b * 2 * HW + HW + pos];
    Taps tp = make_taps((float)yy + fy, (float)xx + fx);

    const float* nb = nbr + (size_t)b * 64 * HW;
    const float* rf = ref + (size_t)b * 64 * HW;
    #pragma unroll
    for (int j = 0; j < 16; ++j) {
        int c = qq * 16 + j;
        const float* pc = nb + c * HW;
        float v = tp.w00 * pc[tp.i00] + tp.w01 * pc[tp.i01] +
                  tp.w10 * pc[tp.i10] + tp.w11 * pc[tp.i11];
        tile[px * 130 + c] = f2bf(v);
        tile[px * 130 + 64 + c] = f2bf(rf[c * HW + pos]);
    }
    __syncthreads();

    short* xo = X1 + ((size_t)b * HW + grp * 64) * 128;
    #pragma unroll
    for (int f8 = threadIdx.x; f8 < 1024; f8 += 256) {
        int p = (f8 * 8) >> 7;
        int c = (f8 * 8) & 127;
        short8 v;
        #pragma unroll
        for (int j = 0; j < 8; ++j) v[j] = tile[p * 130 + c + j];
        *(short8*)(xo + f8 * 8) = v;
    }
}

// ---------------------------------------------------------------------------
// pack_nbr: nbr (B,64,HW) f32 -> N2 (B,HW,64) bf16 via LDS transpose.
// ---------------------------------------------------------------------------
__global__ __launch_bounds__(256) void pack_nbr_kernel(
    const float* __restrict__ nbr, short* __restrict__ N2)
{
    __shared__ short tile[64 * 66];
    int blk = blockIdx.x;              // b*1024 + grp
    int b = blk >> 10;
    int grp = blk & 1023;
    int px = threadIdx.x & 63;
    int qq = threadIdx.x >> 6;
    int pos = grp * 64 + px;

    const float* nb = nbr + (size_t)b * 64 * HW;
    #pragma unroll
    for (int j = 0; j < 16; ++j) {
        int c = qq * 16 + j;
        tile[px * 66 + c] = f2bf(nb[c * HW + pos]);
    }
    __syncthreads();

    short* xo = N2 + ((size_t)b * HW + grp * 64) * 64;
    #pragma unroll
    for (int f8 = threadIdx.x; f8 < 512; f8 += 256) {
        int p = f8 >> 3;
        int c = (f8 & 7) * 8;
        short8 v;
        #pragma unroll
        for (int j = 0; j < 8; ++j) v[j] = tile[p * 66 + c + j];
        *(short8*)(xo + f8 * 8) = v;
    }
}

// ---------------------------------------------------------------------------
// pack_x2_flow: fill X2 channels 64..95 (flow bf16 + zero pad).
// ---------------------------------------------------------------------------
__global__ __launch_bounds__(256) void pack_x2_flow_kernel(
    const float* __restrict__ flow, short* __restrict__ X2)
{
    int t = blockIdx.x * 256 + threadIdx.x;   // 2*HW
    int b = t >> 16;
    int pos = t & (HW - 1);
    short bx = f2bf(flow[b * 2 * HW + pos]);
    short by = f2bf(flow[b * 2 * HW + HW + pos]);
    short* p = X2 + ((size_t)b * HW + pos) * 96 + 64;
    short8 first = {bx, by, 0, 0, 0, 0, 0, 0};
    short8 z = {0, 0, 0, 0, 0, 0, 0, 0};
    *(short8*)(p) = first;
    *(short8*)(p + 8) = z;
    *(short8*)(p + 16) = z;
    *(short8*)(p + 24) = z;
}

// ---------------------------------------------------------------------------
// Weight repacks to MFMA B-fragment order.
// ---------------------------------------------------------------------------
__global__ __launch_bounds__(256) void repack_w1_kernel(
    const float* __restrict__ w, short* __restrict__ wr)
{
    int t = blockIdx.x * 256 + threadIdx.x;  // 73728
    int j = t & 7, q = (t >> 3) & 3, l = (t >> 5) & 15;
    int nt = (t >> 9) & 3, kc = t >> 11;
    int k = kc * 32 + q * 8 + j;
    int rs = k >> 7, c = k & 127;
    int n = nt * 16 + l;
    wr[t] = f2bf(w[(n * 128 + c) * 9 + rs]);
}

__global__ __launch_bounds__(256) void repack_w2_kernel(
    const float* __restrict__ w, short* __restrict__ wr)
{
    int t = blockIdx.x * 256 + threadIdx.x;  // 221184
    int j = t & 7, q = (t >> 3) & 3, l = (t >> 5) & 15;
    int nt = (t >> 9) & 15, kc = t >> 13;
    int k = kc * 32 + q * 8 + j;
    int rs = k / 96, c = k % 96;
    int n = nt * 16 + l;
    float v = (n < 216 && c < 66) ? w[(n * 66 + c) * 9 + rs] : 0.f;
    wr[t] = f2bf(v);
}

// dcn weights -> B-frag order: flat = (((g*3+kc)*4+nt)*64 + l15*4+q)*8 + j
__global__ __launch_bounds__(256) void repack_dcn_kernel(
    const float* __restrict__ w, short* __restrict__ wr)
{
    int t = blockIdx.x * 256 + threadIdx.x;   // 49152
    int j = t & 7, q = (t >> 3) & 3, l = (t >> 5) & 15;
    int rem = t >> 9;           // (g*3+kc)*4 + nt
    int nt = rem & 3;
    int gkc = rem >> 2;         // g*3 + kc
    int kc = gkc % 3, g = gkc / 3;
    int Kidx = kc * 32 + q * 8 + j;
    int k = Kidx >> 3, c = Kidx & 7;
    int och = nt * 16 + l;
    float v = (k < 9) ? w[(och * 64 + g * 8 + c) * 9 + k] : 0.f;
    wr[t] = f2bf(v);
}

// ---------------------------------------------------------------------------
// conv1 MFMA: X1 (NHWC bf16, 128ch) -> fea ch 0..63 of X2 (NHWC bf16, 96).
// ---------------------------------------------------------------------------
#define PADC1 136
__global__ __launch_bounds__(256) void conv1_mfma_kernel(
    const short* __restrict__ X1, const float* __restrict__ bias,
    const short* __restrict__ wr, short* __restrict__ X2)
{
    __shared__ short lds[3 * 66 * PADC1];
    const int tid = threadIdx.x;
    const int w = __builtin_amdgcn_readfirstlane(tid >> 6);
    const int l15 = tid & 15;
    const int q = (tid >> 4) & 3;
    const int blk = ((blockIdx.x & 7) << 8) | (blockIdx.x >> 3);  // XCD swizzle (2048 % 8 == 0)
    const int xseg = blk & 3;
    const int yy = (blk >> 2) & 255;
    const int b = blk >> 10;
    const int x0 = xseg * 64;

    const short* xin = X1 + (size_t)b * HW * 128;
    for (int i = tid; i < 198 * 16; i += 256) {
        int c16 = i & 15;
        int pix = i >> 4;
        int r = pix / 66, xx = pix % 66;
        int gy = yy + r - 1, gx = x0 + xx - 1;
        short8 v = {0, 0, 0, 0, 0, 0, 0, 0};
        if (gy >= 0 && gy < HT && gx >= 0 && gx < WD)
            v = *(const short8*)(xin + ((size_t)((gy << 8) + gx)) * 128 + c16 * 8);
        *(short8*)(&lds[(r * 66 + xx) * PADC1 + c16 * 8]) = v;
    }
    __syncthreads();

    f32x4 acc[4] = {{0,0,0,0},{0,0,0,0},{0,0,0,0},{0,0,0,0}};
    const int bbase = l15 * 4 + q;
    const int abase = l15 * PADC1 + q * 8;

    #define LOADB1(kc_) (*(const short8*)(wr + ((size_t)(((kc_) * 4 + w) * 64 + bbase)) * 8))
    #define COMP1(kc_, bf_) { \
        int rs_ = (kc_) >> 2, cc_ = (kc_) & 3; \
        int r_ = rs_ / 3, s_ = rs_ % 3; \
        int ao_ = (r_ * 66 + s_) * PADC1 + cc_ * 32 + abase; \
        _Pragma("unroll") \
        for (int mt = 0; mt < 4; ++mt) { \
            short8 a_ = *(const short8*)(&lds[ao_ + mt * 16 * PADC1]); \
            acc[mt] = __builtin_amdgcn_mfma_f32_16x16x32_bf16(a_, bf_, acc[mt], 0, 0, 0); \
        } }

    short8 bA = LOADB1(0), bB;
    #pragma unroll 1
    for (int jj = 0; jj < 18; ++jj) {
        int kc0 = 2 * jj;
        bB = LOADB1(kc0 + 1);
        COMP1(kc0, bA);
        int kc2 = kc0 + 2; if (kc2 > 35) kc2 = 35;
        bA = LOADB1(kc2);
        COMP1(kc0 + 1, bB);
    }
    #undef LOADB1
    #undef COMP1

    float bv = bias[w * 16 + l15];
    short* xo = X2 + (size_t)b * HW * 96;
    #pragma unroll
    for (int mt = 0; mt < 4; ++mt) {
        #pragma unroll
        for (int rg = 0; rg < 4; ++rg) {
            int px = x0 + mt * 16 + q * 4 + rg;
            float v = fmaxf(acc[mt][rg] + bv, 0.f);
            xo[((size_t)((yy << 8) + px)) * 96 + w * 16 + l15] = f2bf(v);
        }
    }
}

// ---------------------------------------------------------------------------
// om MFMA: X2 (NHWC bf16, 96ch) -> omraw (B,216,HW) fp32. XCD-swizzled.
// ---------------------------------------------------------------------------
#define PADC2 104
__global__ __launch_bounds__(256) void om_mfma_kernel(
    const short* __restrict__ X2, const short* __restrict__ wr,
    const float* __restrict__ bias, float* __restrict__ omraw)
{
    __shared__ short lds[3 * 66 * PADC2];
    const int tid = threadIdx.x;
    const int w = __builtin_amdgcn_readfirstlane(tid >> 6);
    const int l15 = tid & 15;
    const int q = (tid >> 4) & 3;
    const int blk = ((blockIdx.x & 7) << 8) | (blockIdx.x >> 3);  // XCD swizzle
    const int xseg = blk & 3;
    const int yy = (blk >> 2) & 255;
    const int b = blk >> 10;
    const int x0 = xseg * 64;

    const short* xin = X2 + (size_t)b * HW * 96;
    for (int i = tid; i < 198 * 12; i += 256) {
        int pix = i / 12;
        int c8 = i - pix * 12;
        int r = pix / 66, xx = pix % 66;
        int gy = yy + r - 1, gx = x0 + xx - 1;
        short8 v = {0, 0, 0, 0, 0, 0, 0, 0};
        if (gy >= 0 && gy < HT && gx >= 0 && gx < WD)
            v = *(const short8*)(xin + ((size_t)((gy << 8) + gx)) * 96 + c8 * 8);
        *(short8*)(&lds[(r * 66 + xx) * PADC2 + c8 * 8]) = v;
    }
    __syncthreads();

    f32x4 acc[4][4];
    #pragma unroll
    for (int i = 0; i < 4; ++i)
        #pragma unroll
        for (int mt = 0; mt < 4; ++mt) acc[i][mt] = (f32x4){0,0,0,0};

    const int bbase = l15 * 4 + q;
    const int abase = l15 * PADC2 + q * 8;

    #define LOADB2(dst_, kc_) { \
        _Pragma("unroll") \
        for (int i = 0; i < 4; ++i) \
            dst_[i] = *(const short8*)(wr + ((size_t)(((kc_) * 16 + w * 4 + i) * 64 + bbase)) * 8); }
    #define COMP2(kc_, bf_) { \
        int r_ = (kc_) / 9, s_ = ((kc_) / 3) % 3, cc_ = (kc_) % 3; \
        int ao_ = (r_ * 66 + s_) * PADC2 + cc_ * 32 + abase; \
        short8 a_[4]; \
        _Pragma("unroll") \
        for (int mt = 0; mt < 4; ++mt) \
            a_[mt] = *(const short8*)(&lds[ao_ + mt * 16 * PADC2]); \
        _Pragma("unroll") \
        for (int i = 0; i < 4; ++i) \
            _Pragma("unroll") \
            for (int mt = 0; mt < 4; ++mt) \
                acc[i][mt] = __builtin_amdgcn_mfma_f32_16x16x32_bf16(a_[mt], bf_[i], acc[i][mt], 0, 0, 0); }

    short8 bA[4], bB[4];
    LOADB2(bA, 0);
    #pragma unroll 1
    for (int jj = 0; jj < 13; ++jj) {
        int kc0 = 2 * jj;
        LOADB2(bB, kc0 + 1);
        COMP2(kc0, bA);
        LOADB2(bA, kc0 + 2);
        COMP2(kc0 + 1, bB);
    }
    COMP2(26, bA);
    #undef LOADB2
    #undef COMP2

    float* ldsT = (float*)lds;
    const int LT = 67;
    #pragma unroll 1
    for (int pass = 0; pass < 2; ++pass) {
        __syncthreads();
        if ((w >> 1) == pass) {
            int wl = w & 1;
            #pragma unroll
            for (int i = 0; i < 4; ++i) {
                int chl = (wl * 4 + i) * 16 + l15;
                #pragma unroll
                for (int mt = 0; mt < 4; ++mt)
                    #pragma unroll
                    for (int rg = 0; rg < 4; ++rg)
                        ldsT[chl * LT + mt * 16 + q * 4 + rg] = acc[i][mt][rg];
            }
        }
        __syncthreads();
        int chbase = pass * 128;
        for (int f = tid; f < 128 * 64; f += 256) {
            int chl = f >> 6, px = f & 63;
            int ch = chbase + chl;
            if (ch < 216) {
                float v = ldsT[chl * LT + px] + bias[ch];
                omraw[((size_t)b * 216 + ch) * HW + (yy << 8) + x0 + px] = v;
            }
        }
    }
}

// ---------------------------------------------------------------------------
// dcn MFMA — register-direct A-fragments (no main-loop LDS, no barriers).
// Key identity: for mfma_f32_16x16x32_bf16, A-frag lane (q,l15) holds
// row l15, K = q*8..q*8+7 of the chunk = tap (4*kc+q), channels 0..7.
// So: wave w owns M-tile w (16 pixels); lane (q,l15) gathers+blends taps
// {q, q+4, q+8} of pixel w*16+l15 -> the blend results ARE the A-fragments
// for kc=0,1,2. Each wave runs all 8 groups independently, accumulating
// all 64 och in acc[4] (16 VGPR). One barrier total (epilogue transpose).
// Raw offsets for g+1 prefetched after the gathers (round-1 trick).
// ---------------------------------------------------------------------------
__global__ __launch_bounds__(256, 3) void dcn_mfma_kernel(
    const float* __restrict__ raw,    // (B,216,HW)
    const float* __restrict__ flow,   // (B,2,HW)
    const short* __restrict__ N2,     // (B,HW,64) bf16
    const short* __restrict__ wrd,    // B-frag order, 49152
    const float* __restrict__ bias,   // 64
    float* __restrict__ out)          // (B,64,HW)
{
    __shared__ __align__(16) float ldsT[64 * 65];   // 16.6 KB, epilogue only

    const int tid = threadIdx.x;
    const int w = __builtin_amdgcn_readfirstlane(tid >> 6);  // M-tile
    const int lane = tid & 63;
    const int l15 = lane & 15;
    const int q = lane >> 4;          // tap-group (tap % 4)

    const int blk = ((blockIdx.x & 7) << 8) | (blockIdx.x >> 3);  // XCD swizzle
    const int b = blk >> 10;
    const int grp = blk & 1023;
    const int pos0 = grp * 64;
    const int p = pos0 + w * 16 + l15;     // this lane's pixel
    const int yy = p >> 8, xx = p & 255;

    const float* rawp = raw + (size_t)b * 216 * HW + p;
    const float fx = flow[b * 2 * HW + p];
    const float fy = flow[b * 2 * HW + HW + p];
    const short* nb2 = N2 + (size_t)b * HW * 64;

    f32x4 acc[4];
    #pragma unroll
    for (int ot = 0; ot < 4; ++ot) acc[ot] = (f32x4){0, 0, 0, 0};

    // prologue: raw offset/mask loads for g=0.
    // lane's taps: t = q + 4*it; it==2 valid only for q==0 (tap 8).
    float rdy[3], rdx[3], rm[3];
    #pragma unroll
    for (int it = 0; it < 3; ++it) {
        const int t = q + 4 * it;
        const bool valid = (it < 2) || (q == 0);
        rdy[it] = 0.f; rdx[it] = 0.f; rm[it] = 0.f;
        if (valid) {
            rdy[it] = rawp[(size_t)(2 * t) * HW];
            rdx[it] = rawp[(size_t)(2 * t + 1) * HW];
            rm[it]  = rawp[(size_t)(144 + t) * HW];
        }
    }

    #pragma unroll 1
    for (int g = 0; g < 8; ++g) {
        const short* nbg = nb2 + g * 8;

        // --- tap math + gather issue (12 gathers in flight) ---
        float w00[3], w01[3], w10[3], w11[3];
        short8 a00[3], a01[3], a10[3], a11[3];
        #pragma unroll
        for (int it = 0; it < 3; ++it) {
            const int t = q + 4 * it;
            const bool valid = (it < 2) || (q == 0);
            if (valid) {
                float dy = rdy[it] + fy;
                float dx = rdx[it] + fx;
                float m = 1.f / (1.f + __expf(-rm[it]));
                float py  = (float)(yy - 1 + t / 3) + dy;
                float pxx = (float)(xx - 1 + t % 3) + dx;
                Taps tp = make_taps(py, pxx);
                w00[it] = tp.w00 * m; w01[it] = tp.w01 * m;
                w10[it] = tp.w10 * m; w11[it] = tp.w11 * m;
                a00[it] = *(const short8*)(nbg + (size_t)tp.i00 * 64);
                a01[it] = *(const short8*)(nbg + (size_t)tp.i01 * 64);
                a10[it] = *(const short8*)(nbg + (size_t)tp.i10 * 64);
                a11[it] = *(const short8*)(nbg + (size_t)tp.i11 * 64);
            }
        }

        // --- prefetch next group's raw values (issued after the gathers so
        //     the gather waitcnt leaves these in flight) ---
        if (g < 7) {
            const float* rgn = rawp + (size_t)((g + 1) * 18) * HW;
            const float* rmn = rawp + (size_t)(144 + (g + 1) * 9) * HW;
            #pragma unroll
            for (int it = 0; it < 3; ++it) {
                const int t = q + 4 * it;
                const bool valid = (it < 2) || (q == 0);
                if (valid) {
                    rdy[it] = rgn[(size_t)(2 * t) * HW];
                    rdx[it] = rgn[(size_t)(2 * t + 1) * HW];
                    rm[it]  = rmn[(size_t)t * HW];
                }
            }
        }

        // --- blend -> A-fragments in-register ---
        short8 afrag[3];
        #pragma unroll
        for (int it = 0; it < 3; ++it) {
            const bool valid = (it < 2) || (q == 0);
            union { bf16x8 bv; short8 s; } u;
            u.s = (short8){0, 0, 0, 0, 0, 0, 0, 0};
            if (valid) {
                #pragma unroll
                for (int c = 0; c < 8; ++c) {
                    float s = w00[it] * bf2f(a00[it][c]) + w01[it] * bf2f(a01[it][c]) +
                              w10[it] * bf2f(a10[it][c]) + w11[it] * bf2f(a11[it][c]);
                    u.bv[c] = (__bf16)s;
                }
            }
            afrag[it] = u.s;
        }

        // --- MFMA: 3 K-chunks x 4 och-tiles, A straight from registers ---
        #pragma unroll
        for (int kc = 0; kc < 3; ++kc) {
            short8 bf[4];
            #pragma unroll
            for (int ot = 0; ot < 4; ++ot)
                bf[ot] = *(const short8*)(wrd +
                    ((size_t)(((g * 3 + kc) * 4 + ot) * 64 + l15 * 4 + q)) * 8);
            #pragma unroll
            for (int ot = 0; ot < 4; ++ot)
                acc[ot] = __builtin_amdgcn_mfma_f32_16x16x32_bf16(
                    afrag[kc], bf[ot], acc[ot], 0, 0, 0);
        }
    }

    // epilogue: D lane (q,l15) holds pixel (w*16 + q*4 + rg), och (ot*16+l15).
    // Transpose via LDS -> coalesced NCHW stores (+bias).
    #pragma unroll
    for (int ot = 0; ot < 4; ++ot)
        #pragma unroll
        for (int rg = 0; rg < 4; ++rg)
            ldsT[(ot * 16 + l15) * 65 + w * 16 + q * 4 + rg] = acc[ot][rg];
    __syncthreads();
    float* ob = out + (size_t)b * 64 * HW + pos0;
    for (int f = tid; f < 4096; f += 256) {
        int och = f >> 6, p2 = f & 63;
        ob[(size_t)och * HW + p2] = ldsT[och * 65 + p2] + bias[och];
    }
}

// ---------------------------------------------------------------------------
extern "C" void kernel_launch(void* const* d_in, const int* in_sizes, int n_in,
                              void* d_out, int out_size, void* d_ws, size_t ws_size,
                              hipStream_t stream)
{
    const float* nbr  = (const float*)d_in[0];
    const float* ref  = (const float*)d_in[1];
    const float* flow = (const float*)d_in[2];
    const float* c1w  = (const float*)d_in[3];
    const float* c1b  = (const float*)d_in[4];
    const float* omw  = (const float*)d_in[5];
    const float* omb  = (const float*)d_in[6];
    const float* dw   = (const float*)d_in[7];
    const float* db   = (const float*)d_in[8];
    float* out = (float*)d_out;

    char* wsb = (char*)d_ws;
    short* X1    = (short*)(wsb);                  // 33,554,432 B
    short* X2    = (short*)(wsb + 33554432);       // 25,165,824 B
    float* omraw = (float*)(wsb + 58720256);       // 113,246,208 B
    short* wr1   = (short*)(wsb + 171966464);      // 147,456 B
    short* wr2   = (short*)(wsb + 172113920);      // 442,368 B
    short* wrd   = (short*)(wsb + 172556288);      // 98,304 B
    // N2 aliases X1: X1 is dead after conv1_mfma; stream serializes kernels.
    short* N2    = X1;                             // 16,777,216 B

    repack_w1_kernel<<<288, 256, 0, stream>>>(c1w, wr1);
    repack_w2_kernel<<<864, 256, 0, stream>>>(omw, wr2);
    repack_dcn_kernel<<<192, 256, 0, stream>>>(dw, wrd);
    pack_x1_kernel<<<2048, 256, 0, stream>>>(nbr, ref, flow, X1);
    pack_x2_flow_kernel<<<512, 256, 0, stream>>>(flow, X2);
    conv1_mfma_kernel<<<2048, 256, 0, stream>>>(X1, c1b, wr1, X2);
    pack_nbr_kernel<<<2048, 256, 0, stream>>>(nbr, N2);   // overwrites X1
    om_mfma_kernel<<<2048, 256, 0, stream>>>(X2, wr2, omb, omraw);
    dcn_mfma_kernel<<<2048, 256, 0, stream>>>(omraw, flow, N2, wrd, db, out);
}

// Round 5
// 424.827 us; speedup vs baseline: 1.0681x; 1.0366x over previous
//
#include <hip/hip_runtime.h>
#include <math.h>

#define HW 65536
#define WD 256
#define HT 256

typedef short short8 __attribute__((ext_vector_type(8)));
typedef float f32x4 __attribute__((ext_vector_type(4)));
typedef __bf16 bf16x8 __attribute__((ext_vector_type(8)));

__device__ __forceinline__ short f2bf(float f) {
    union { float f; unsigned u; } v; v.f = f;
    unsigned r = (v.u + 0x7fffu + ((v.u >> 16) & 1u)) >> 16;
    return (short)r;
}

__device__ __forceinline__ float bf2f(short s) {
    union { unsigned u; float f; } v;
    v.u = ((unsigned)(unsigned short)s) << 16;
    return v.f;
}

__device__ __forceinline__ int iclamp(int v, int lo, int hi) {
    return v < lo ? lo : (v > hi ? hi : v);
}

struct Taps {
    int i00, i01, i10, i11;
    float w00, w01, w10, w11;
};

__device__ __forceinline__ Taps make_taps(float py, float px) {
    float fy0 = floorf(py), fx0 = floorf(px);
    float wy = py - fy0, wx = px - fx0;
    int y0 = (int)fy0, x0 = (int)fx0;
    int y1 = y0 + 1, x1 = x0 + 1;
    float vy0 = (y0 >= 0 && y0 <= HT - 1) ? 1.f : 0.f;
    float vy1 = (y1 >= 0 && y1 <= HT - 1) ? 1.f : 0.f;
    float vx0 = (x0 >= 0 && x0 <= WD - 1) ? 1.f : 0.f;
    float vx1 = (x1 >= 0 && x1 <= WD - 1) ? 1.f : 0.f;
    int yc0 = iclamp(y0, 0, HT - 1), yc1 = iclamp(y1, 0, HT - 1);
    int xc0 = iclamp(x0, 0, WD - 1), xc1 = iclamp(x1, 0, WD - 1);
    Taps t;
    t.i00 = yc0 * WD + xc0; t.i01 = yc0 * WD + xc1;
    t.i10 = yc1 * WD + xc0; t.i11 = yc1 * WD + xc1;
    t.w00 = (1.f - wy) * (1.f - wx) * vy0 * vx0;
    t.w01 = (1.f - wy) * wx * vy0 * vx1;
    t.w10 = wy * (1.f - wx) * vy1 * vx0;
    t.w11 = wy * wx * vy1 * vx1;
    return t;
}

// ---------------------------------------------------------------------------
// pack_x1: warp(nbr) + ref -> X1 (B,HW,128) NHWC bf16, via LDS transpose.
// ---------------------------------------------------------------------------
__global__ __launch_bounds__(256) void pack_x1_kernel(
    const float* __restrict__ nbr, const float* __restrict__ ref,
    const float* __restrict__ flow, short* __restrict__ X1)
{
    __shared__ short tile[64 * 130];
    int blk = blockIdx.x;              // b*1024 + grp
    int b = blk >> 10;
    int grp = blk & 1023;
    int px = threadIdx.x & 63;
    int qq = threadIdx.x >> 6;
    int pos = grp * 64 + px;
    int yy = pos >> 8, xx = pos & 255;

    float fx = flow[b * 2 * HW + pos];
    float fy = flow[b * 2 * HW + HW + pos];
    Taps tp = make_taps((float)yy + fy, (float)xx + fx);

    const float* nb = nbr + (size_t)b * 64 * HW;
    const float* rf = ref + (size_t)b * 64 * HW;
    #pragma unroll
    for (int j = 0; j < 16; ++j) {
        int c = qq * 16 + j;
        const float* pc = nb + c * HW;
        float v = tp.w00 * pc[tp.i00] + tp.w01 * pc[tp.i01] +
                  tp.w10 * pc[tp.i10] + tp.w11 * pc[tp.i11];
        tile[px * 130 + c] = f2bf(v);
        tile[px * 130 + 64 + c] = f2bf(rf[c * HW + pos]);
    }
    __syncthreads();

    short* xo = X1 + ((size_t)b * HW + grp * 64) * 128;
    #pragma unroll
    for (int f8 = threadIdx.x; f8 < 1024; f8 += 256) {
        int p = (f8 * 8) >> 7;
        int c = (f8 * 8) & 127;
        short8 v;
        #pragma unroll
        for (int j = 0; j < 8; ++j) v[j] = tile[p * 130 + c + j];
        *(short8*)(xo + f8 * 8) = v;
    }
}

// ---------------------------------------------------------------------------
// pack_nbr: nbr (B,64,HW) f32 -> N2 (B,HW,64) bf16 via LDS transpose.
// ---------------------------------------------------------------------------
__global__ __launch_bounds__(256) void pack_nbr_kernel(
    const float* __restrict__ nbr, short* __restrict__ N2)
{
    __shared__ short tile[64 * 66];
    int blk = blockIdx.x;              // b*1024 + grp
    int b = blk >> 10;
    int grp = blk & 1023;
    int px = threadIdx.x & 63;
    int qq = threadIdx.x >> 6;
    int pos = grp * 64 + px;

    const float* nb = nbr + (size_t)b * 64 * HW;
    #pragma unroll
    for (int j = 0; j < 16; ++j) {
        int c = qq * 16 + j;
        tile[px * 66 + c] = f2bf(nb[c * HW + pos]);
    }
    __syncthreads();

    short* xo = N2 + ((size_t)b * HW + grp * 64) * 64;
    #pragma unroll
    for (int f8 = threadIdx.x; f8 < 512; f8 += 256) {
        int p = f8 >> 3;
        int c = (f8 & 7) * 8;
        short8 v;
        #pragma unroll
        for (int j = 0; j < 8; ++j) v[j] = tile[p * 66 + c + j];
        *(short8*)(xo + f8 * 8) = v;
    }
}

// ---------------------------------------------------------------------------
// pack_x2_flow: fill X2 channels 64..95 (flow bf16 + zero pad).
// ---------------------------------------------------------------------------
__global__ __launch_bounds__(256) void pack_x2_flow_kernel(
    const float* __restrict__ flow, short* __restrict__ X2)
{
    int t = blockIdx.x * 256 + threadIdx.x;   // 2*HW
    int b = t >> 16;
    int pos = t & (HW - 1);
    short bx = f2bf(flow[b * 2 * HW + pos]);
    short by = f2bf(flow[b * 2 * HW + HW + pos]);
    short* p = X2 + ((size_t)b * HW + pos) * 96 + 64;
    short8 first = {bx, by, 0, 0, 0, 0, 0, 0};
    short8 z = {0, 0, 0, 0, 0, 0, 0, 0};
    *(short8*)(p) = first;
    *(short8*)(p + 8) = z;
    *(short8*)(p + 16) = z;
    *(short8*)(p + 24) = z;
}

// ---------------------------------------------------------------------------
// Weight repacks to MFMA B-fragment order.
// ---------------------------------------------------------------------------
__global__ __launch_bounds__(256) void repack_w1_kernel(
    const float* __restrict__ w, short* __restrict__ wr)
{
    int t = blockIdx.x * 256 + threadIdx.x;  // 73728
    int j = t & 7, q = (t >> 3) & 3, l = (t >> 5) & 15;
    int nt = (t >> 9) & 3, kc = t >> 11;
    int k = kc * 32 + q * 8 + j;
    int rs = k >> 7, c = k & 127;
    int n = nt * 16 + l;
    wr[t] = f2bf(w[(n * 128 + c) * 9 + rs]);
}

__global__ __launch_bounds__(256) void repack_w2_kernel(
    const float* __restrict__ w, short* __restrict__ wr)
{
    int t = blockIdx.x * 256 + threadIdx.x;  // 221184
    int j = t & 7, q = (t >> 3) & 3, l = (t >> 5) & 15;
    int nt = (t >> 9) & 15, kc = t >> 13;
    int k = kc * 32 + q * 8 + j;
    int rs = k / 96, c = k % 96;
    int n = nt * 16 + l;
    float v = (n < 216 && c < 66) ? w[(n * 66 + c) * 9 + rs] : 0.f;
    wr[t] = f2bf(v);
}

// dcn weights -> B-frag order: flat = (((g*3+kc)*4+nt)*64 + l15*4+q)*8 + j
__global__ __launch_bounds__(256) void repack_dcn_kernel(
    const float* __restrict__ w, short* __restrict__ wr)
{
    int t = blockIdx.x * 256 + threadIdx.x;   // 49152
    int j = t & 7, q = (t >> 3) & 3, l = (t >> 5) & 15;
    int rem = t >> 9;           // (g*3+kc)*4 + nt
    int nt = rem & 3;
    int gkc = rem >> 2;         // g*3 + kc
    int kc = gkc % 3, g = gkc / 3;
    int Kidx = kc * 32 + q * 8 + j;
    int k = Kidx >> 3, c = Kidx & 7;
    int och = nt * 16 + l;
    float v = (k < 9) ? w[(och * 64 + g * 8 + c) * 9 + k] : 0.f;
    wr[t] = f2bf(v);
}

// ---------------------------------------------------------------------------
// conv1 MFMA: X1 (NHWC bf16, 128ch) -> fea ch 0..63 of X2 (NHWC bf16, 96).
// ---------------------------------------------------------------------------
#define PADC1 136
__global__ __launch_bounds__(256) void conv1_mfma_kernel(
    const short* __restrict__ X1, const float* __restrict__ bias,
    const short* __restrict__ wr, short* __restrict__ X2)
{
    __shared__ short lds[3 * 66 * PADC1];
    const int tid = threadIdx.x;
    const int w = __builtin_amdgcn_readfirstlane(tid >> 6);
    const int l15 = tid & 15;
    const int q = (tid >> 4) & 3;
    const int blk = ((blockIdx.x & 7) << 8) | (blockIdx.x >> 3);  // XCD swizzle (2048 % 8 == 0)
    const int xseg = blk & 3;
    const int yy = (blk >> 2) & 255;
    const int b = blk >> 10;
    const int x0 = xseg * 64;

    const short* xin = X1 + (size_t)b * HW * 128;
    for (int i = tid; i < 198 * 16; i += 256) {
        int c16 = i & 15;
        int pix = i >> 4;
        int r = pix / 66, xx = pix % 66;
        int gy = yy + r - 1, gx = x0 + xx - 1;
        short8 v = {0, 0, 0, 0, 0, 0, 0, 0};
        if (gy >= 0 && gy < HT && gx >= 0 && gx < WD)
            v = *(const short8*)(xin + ((size_t)((gy << 8) + gx)) * 128 + c16 * 8);
        *(short8*)(&lds[(r * 66 + xx) * PADC1 + c16 * 8]) = v;
    }
    __syncthreads();

    f32x4 acc[4] = {{0,0,0,0},{0,0,0,0},{0,0,0,0},{0,0,0,0}};
    const int bbase = l15 * 4 + q;
    const int abase = l15 * PADC1 + q * 8;

    #define LOADB1(kc_) (*(const short8*)(wr + ((size_t)(((kc_) * 4 + w) * 64 + bbase)) * 8))
    #define COMP1(kc_, bf_) { \
        int rs_ = (kc_) >> 2, cc_ = (kc_) & 3; \
        int r_ = rs_ / 3, s_ = rs_ % 3; \
        int ao_ = (r_ * 66 + s_) * PADC1 + cc_ * 32 + abase; \
        _Pragma("unroll") \
        for (int mt = 0; mt < 4; ++mt) { \
            short8 a_ = *(const short8*)(&lds[ao_ + mt * 16 * PADC1]); \
            acc[mt] = __builtin_amdgcn_mfma_f32_16x16x32_bf16(a_, bf_, acc[mt], 0, 0, 0); \
        } }

    short8 bA = LOADB1(0), bB;
    #pragma unroll 1
    for (int jj = 0; jj < 18; ++jj) {
        int kc0 = 2 * jj;
        bB = LOADB1(kc0 + 1);
        COMP1(kc0, bA);
        int kc2 = kc0 + 2; if (kc2 > 35) kc2 = 35;
        bA = LOADB1(kc2);
        COMP1(kc0 + 1, bB);
    }
    #undef LOADB1
    #undef COMP1

    float bv = bias[w * 16 + l15];
    short* xo = X2 + (size_t)b * HW * 96;
    #pragma unroll
    for (int mt = 0; mt < 4; ++mt) {
        #pragma unroll
        for (int rg = 0; rg < 4; ++rg) {
            int px = x0 + mt * 16 + q * 4 + rg;
            float v = fmaxf(acc[mt][rg] + bv, 0.f);
            xo[((size_t)((yy << 8) + px)) * 96 + w * 16 + l15] = f2bf(v);
        }
    }
}

// ---------------------------------------------------------------------------
// om MFMA: X2 (NHWC bf16, 96ch) -> omraw (B,216,HW) fp32. XCD-swizzled.
// ---------------------------------------------------------------------------
#define PADC2 104
__global__ __launch_bounds__(256) void om_mfma_kernel(
    const short* __restrict__ X2, const short* __restrict__ wr,
    const float* __restrict__ bias, float* __restrict__ omraw)
{
    __shared__ short lds[3 * 66 * PADC2];
    const int tid = threadIdx.x;
    const int w = __builtin_amdgcn_readfirstlane(tid >> 6);
    const int l15 = tid & 15;
    const int q = (tid >> 4) & 3;
    const int blk = ((blockIdx.x & 7) << 8) | (blockIdx.x >> 3);  // XCD swizzle
    const int xseg = blk & 3;
    const int yy = (blk >> 2) & 255;
    const int b = blk >> 10;
    const int x0 = xseg * 64;

    const short* xin = X2 + (size_t)b * HW * 96;
    for (int i = tid; i < 198 * 12; i += 256) {
        int pix = i / 12;
        int c8 = i - pix * 12;
        int r = pix / 66, xx = pix % 66;
        int gy = yy + r - 1, gx = x0 + xx - 1;
        short8 v = {0, 0, 0, 0, 0, 0, 0, 0};
        if (gy >= 0 && gy < HT && gx >= 0 && gx < WD)
            v = *(const short8*)(xin + ((size_t)((gy << 8) + gx)) * 96 + c8 * 8);
        *(short8*)(&lds[(r * 66 + xx) * PADC2 + c8 * 8]) = v;
    }
    __syncthreads();

    f32x4 acc[4][4];
    #pragma unroll
    for (int i = 0; i < 4; ++i)
        #pragma unroll
        for (int mt = 0; mt < 4; ++mt) acc[i][mt] = (f32x4){0,0,0,0};

    const int bbase = l15 * 4 + q;
    const int abase = l15 * PADC2 + q * 8;

    #define LOADB2(dst_, kc_) { \
        _Pragma("unroll") \
        for (int i = 0; i < 4; ++i) \
            dst_[i] = *(const short8*)(wr + ((size_t)(((kc_) * 16 + w * 4 + i) * 64 + bbase)) * 8); }
    #define COMP2(kc_, bf_) { \
        int r_ = (kc_) / 9, s_ = ((kc_) / 3) % 3, cc_ = (kc_) % 3; \
        int ao_ = (r_ * 66 + s_) * PADC2 + cc_ * 32 + abase; \
        short8 a_[4]; \
        _Pragma("unroll") \
        for (int mt = 0; mt < 4; ++mt) \
            a_[mt] = *(const short8*)(&lds[ao_ + mt * 16 * PADC2]); \
        _Pragma("unroll") \
        for (int i = 0; i < 4; ++i) \
            _Pragma("unroll") \
            for (int mt = 0; mt < 4; ++mt) \
                acc[i][mt] = __builtin_amdgcn_mfma_f32_16x16x32_bf16(a_[mt], bf_[i], acc[i][mt], 0, 0, 0); }

    short8 bA[4], bB[4];
    LOADB2(bA, 0);
    #pragma unroll 1
    for (int jj = 0; jj < 13; ++jj) {
        int kc0 = 2 * jj;
        LOADB2(bB, kc0 + 1);
        COMP2(kc0, bA);
        LOADB2(bA, kc0 + 2);
        COMP2(kc0 + 1, bB);
    }
    COMP2(26, bA);
    #undef LOADB2
    #undef COMP2

    float* ldsT = (float*)lds;
    const int LT = 67;
    #pragma unroll 1
    for (int pass = 0; pass < 2; ++pass) {
        __syncthreads();
        if ((w >> 1) == pass) {
            int wl = w & 1;
            #pragma unroll
            for (int i = 0; i < 4; ++i) {
                int chl = (wl * 4 + i) * 16 + l15;
                #pragma unroll
                for (int mt = 0; mt < 4; ++mt)
                    #pragma unroll
                    for (int rg = 0; rg < 4; ++rg)
                        ldsT[chl * LT + mt * 16 + q * 4 + rg] = acc[i][mt][rg];
            }
        }
        __syncthreads();
        int chbase = pass * 128;
        for (int f = tid; f < 128 * 64; f += 256) {
            int chl = f >> 6, px = f & 63;
            int ch = chbase + chl;
            if (ch < 216) {
                float v = ldsT[chl * LT + px] + bias[ch];
                omraw[((size_t)b * 216 + ch) * HW + (yy << 8) + x0 + px] = v;
            }
        }
    }
}

// ---------------------------------------------------------------------------
// dcn MFMA — round-1 cooperative structure + double-buffered A-tile with
// cross-group software pipeline (ONE barrier per group):
//   iter g: issue gathers(g+1) -> MFMA(g) from buf[g&1] -> blend(g+1) ->
//           write buf[(g+1)&1] -> barrier
// The N2 gather latency hides under the same wave's ds_read+MFMA phase and
// under other waves. Raw offsets for g+2 prefetched after the gathers.
// Hazards: buf[(g+1)&1] was last READ in iter g-1 (before that iter's
// barrier); the single end-of-iter barrier fences this iter's writes before
// iter g+1's reads. Epilogue aliases the buffers after the final barrier.
// ---------------------------------------------------------------------------
__global__ __launch_bounds__(256) void dcn_mfma_kernel(
    const float* __restrict__ raw,    // (B,216,HW)
    const float* __restrict__ flow,   // (B,2,HW)
    const short* __restrict__ N2,     // (B,HW,64) bf16
    const short* __restrict__ wrd,    // B-frag order, 49152
    const float* __restrict__ bias,   // 64
    float* __restrict__ out)          // (B,64,HW)
{
    __shared__ __align__(16) char ldsraw[26624];
    short* bufA = (short*)ldsraw;                 // [64 px][104]
    short* bufB = (short*)(ldsraw + 13312);       // [64 px][104]
    float* ldsT = (float*)ldsraw;                 // [64 och][65] epilogue alias

    const int tid = threadIdx.x;
    const int w = __builtin_amdgcn_readfirstlane(tid >> 6);
    const int l15 = tid & 15;
    const int q = (tid >> 4) & 3;
    const int qq = tid >> 6;
    const int px = tid & 63;

    const int blk = ((blockIdx.x & 7) << 8) | (blockIdx.x >> 3);  // XCD swizzle
    const int b = blk >> 10;
    const int grp = blk & 1023;
    const int pos0 = grp * 64;
    const int pos = pos0 + px;
    const int yy = pos >> 8, xx = pos & 255;

    const float* rawb = raw + (size_t)b * 216 * HW + pos;
    const float fx = flow[b * 2 * HW + pos];
    const float fy = flow[b * 2 * HW + HW + pos];
    const short* nb2 = N2 + (size_t)b * HW * 64;

    // zero pad K-slots (k = 9..11) in BOTH buffers once
    {
        short8 z = {0, 0, 0, 0, 0, 0, 0, 0};
        #pragma unroll
        for (int it = 0; it < 3; ++it) {
            int k = qq + 4 * it;
            if (k >= 9) {
                *(short8*)(&bufA[px * 104 + k * 8]) = z;
                *(short8*)(&bufB[px * 104 + k * 8]) = z;
            }
        }
    }

    f32x4 acc[4] = {{0,0,0,0},{0,0,0,0},{0,0,0,0},{0,0,0,0}};

    // raw offset/mask loads for g=0
    float rdy[3], rdx[3], rm[3];
    #pragma unroll
    for (int it = 0; it < 3; ++it) {
        int k = qq + 4 * it;
        rdy[it] = 0.f; rdx[it] = 0.f; rm[it] = 0.f;
        if (k < 9) {
            rdy[it] = rawb[(size_t)(2 * k) * HW];
            rdx[it] = rawb[(size_t)(2 * k + 1) * HW];
            rm[it]  = rawb[(size_t)(144 + k) * HW];
        }
    }

    // ---- prologue: fill group 0 into bufA ----
    {
        float w00[3], w01[3], w10[3], w11[3];
        short8 a00[3], a01[3], a10[3], a11[3];
        #pragma unroll
        for (int it = 0; it < 3; ++it) {
            int k = qq + 4 * it;
            if (k < 9) {
                float dy = rdy[it] + fy, dx = rdx[it] + fx;
                float m = 1.f / (1.f + __expf(-rm[it]));
                Taps tp = make_taps((float)(yy - 1 + k / 3) + dy,
                                    (float)(xx - 1 + k % 3) + dx);
                w00[it] = tp.w00 * m; w01[it] = tp.w01 * m;
                w10[it] = tp.w10 * m; w11[it] = tp.w11 * m;
                a00[it] = *(const short8*)(nb2 + (size_t)tp.i00 * 64);
                a01[it] = *(const short8*)(nb2 + (size_t)tp.i01 * 64);
                a10[it] = *(const short8*)(nb2 + (size_t)tp.i10 * 64);
                a11[it] = *(const short8*)(nb2 + (size_t)tp.i11 * 64);
            }
        }
        // prefetch raw g=1 (after the gathers: stays in flight through blend)
        #pragma unroll
        for (int it = 0; it < 3; ++it) {
            int k = qq + 4 * it;
            if (k < 9) {
                rdy[it] = rawb[(size_t)(18 + 2 * k) * HW];
                rdx[it] = rawb[(size_t)(18 + 2 * k + 1) * HW];
                rm[it]  = rawb[(size_t)(144 + 9 + k) * HW];
            }
        }
        #pragma unroll
        for (int it = 0; it < 3; ++it) {
            int k = qq + 4 * it;
            if (k < 9) {
                union { bf16x8 bv; short8 s; } u;
                #pragma unroll
                for (int c = 0; c < 8; ++c) {
                    float s = w00[it] * bf2f(a00[it][c]) + w01[it] * bf2f(a01[it][c]) +
                              w10[it] * bf2f(a10[it][c]) + w11[it] * bf2f(a11[it][c]);
                    u.bv[c] = (__bf16)s;
                }
                *(short8*)(&bufA[px * 104 + k * 8]) = u.s;
            }
        }
    }
    __syncthreads();

    // ---- pipelined main loop: one barrier per group ----
    #pragma unroll 1
    for (int g = 0; g < 8; ++g) {
        short* cur = (g & 1) ? bufB : bufA;
        short* nxt = (g & 1) ? bufA : bufB;

        // issue gathers for group g+1 (12 loads in flight across the MFMAs)
        float w00[3], w01[3], w10[3], w11[3];
        short8 a00[3], a01[3], a10[3], a11[3];
        if (g < 7) {
            const short* nbg = nb2 + (g + 1) * 8;
            #pragma unroll
            for (int it = 0; it < 3; ++it) {
                int k = qq + 4 * it;
                if (k < 9) {
                    float dy = rdy[it] + fy, dx = rdx[it] + fx;
                    float m = 1.f / (1.f + __expf(-rm[it]));
                    Taps tp = make_taps((float)(yy - 1 + k / 3) + dy,
                                        (float)(xx - 1 + k % 3) + dx);
                    w00[it] = tp.w00 * m; w01[it] = tp.w01 * m;
                    w10[it] = tp.w10 * m; w11[it] = tp.w11 * m;
                    a00[it] = *(const short8*)(nbg + (size_t)tp.i00 * 64);
                    a01[it] = *(const short8*)(nbg + (size_t)tp.i01 * 64);
                    a10[it] = *(const short8*)(nbg + (size_t)tp.i10 * 64);
                    a11[it] = *(const short8*)(nbg + (size_t)tp.i11 * 64);
                }
            }
            // prefetch raw for g+2 (after gathers: not drained by their wait)
            if (g < 6) {
                #pragma unroll
                for (int it = 0; it < 3; ++it) {
                    int k = qq + 4 * it;
                    if (k < 9) {
                        rdy[it] = rawb[(size_t)((g + 2) * 18 + 2 * k) * HW];
                        rdx[it] = rawb[(size_t)((g + 2) * 18 + 2 * k + 1) * HW];
                        rm[it]  = rawb[(size_t)(144 + (g + 2) * 9 + k) * HW];
                    }
                }
            }
        }

        // MFMA group g from cur (hides the gather latency)
        #pragma unroll
        for (int kc = 0; kc < 3; ++kc) {
            short8 bfrag = *(const short8*)(wrd +
                ((size_t)(((g * 3 + kc) * 4 + w) * 64 + l15 * 4 + q)) * 8);
            #pragma unroll
            for (int mt = 0; mt < 4; ++mt) {
                short8 a = *(const short8*)(&cur[(mt * 16 + l15) * 104 + kc * 32 + q * 8]);
                acc[mt] = __builtin_amdgcn_mfma_f32_16x16x32_bf16(a, bfrag, acc[mt], 0, 0, 0);
            }
        }

        // blend g+1 -> nxt
        if (g < 7) {
            #pragma unroll
            for (int it = 0; it < 3; ++it) {
                int k = qq + 4 * it;
                if (k < 9) {
                    union { bf16x8 bv; short8 s; } u;
                    #pragma unroll
                    for (int c = 0; c < 8; ++c) {
                        float s = w00[it] * bf2f(a00[it][c]) + w01[it] * bf2f(a01[it][c]) +
                                  w10[it] * bf2f(a10[it][c]) + w11[it] * bf2f(a11[it][c]);
                        u.bv[c] = (__bf16)s;
                    }
                    *(short8*)(&nxt[px * 104 + k * 8]) = u.s;
                }
            }
        }
        __syncthreads();
    }

    // epilogue: LDS transpose -> coalesced NCHW stores (+bias)
    #pragma unroll
    for (int mt = 0; mt < 4; ++mt)
        #pragma unroll
        for (int rg = 0; rg < 4; ++rg)
            ldsT[(w * 16 + l15) * 65 + mt * 16 + q * 4 + rg] = acc[mt][rg];
    __syncthreads();
    float* ob = out + (size_t)b * 64 * HW + pos0;
    for (int f = tid; f < 4096; f += 256) {
        int och = f >> 6, p2 = f & 63;
        ob[(size_t)och * HW + p2] = ldsT[och * 65 + p2] + bias[och];
    }
}

// ---------------------------------------------------------------------------
extern "C" void kernel_launch(void* const* d_in, const int* in_sizes, int n_in,
                              void* d_out, int out_size, void* d_ws, size_t ws_size,
                              hipStream_t stream)
{
    const float* nbr  = (const float*)d_in[0];
    const float* ref  = (const float*)d_in[1];
    const float* flow = (const float*)d_in[2];
    const float* c1w  = (const float*)d_in[3];
    const float* c1b  = (const float*)d_in[4];
    const float* omw  = (const float*)d_in[5];
    const float* omb  = (const float*)d_in[6];
    const float* dw   = (const float*)d_in[7];
    const float* db   = (const float*)d_in[8];
    float* out = (float*)d_out;

    char* wsb = (char*)d_ws;
    short* X1    = (short*)(wsb);                  // 33,554,432 B
    short* X2    = (short*)(wsb + 33554432);       // 25,165,824 B
    float* omraw = (float*)(wsb + 58720256);       // 113,246,208 B
    short* wr1   = (short*)(wsb + 171966464);      // 147,456 B
    short* wr2   = (short*)(wsb + 172113920);      // 442,368 B
    short* wrd   = (short*)(wsb + 172556288);      // 98,304 B
    // N2 aliases X1: X1 is dead after conv1_mfma; stream serializes kernels.
    short* N2    = X1;                             // 16,777,216 B

    repack_w1_kernel<<<288, 256, 0, stream>>>(c1w, wr1);
    repack_w2_kernel<<<864, 256, 0, stream>>>(omw, wr2);
    repack_dcn_kernel<<<192, 256, 0, stream>>>(dw, wrd);
    pack_x1_kernel<<<2048, 256, 0, stream>>>(nbr, ref, flow, X1);
    pack_x2_flow_kernel<<<512, 256, 0, stream>>>(flow, X2);
    conv1_mfma_kernel<<<2048, 256, 0, stream>>>(X1, c1b, wr1, X2);
    pack_nbr_kernel<<<2048, 256, 0, stream>>>(nbr, N2);   // overwrites X1
    om_mfma_kernel<<<2048, 256, 0, stream>>>(X2, wr2, omb, omraw);
    dcn_mfma_kernel<<<2048, 256, 0, stream>>>(omraw, flow, N2, wrd, db, out);
}

// Round 6
// 366.955 us; speedup vs baseline: 1.2365x; 1.1577x over previous
//
#include <hip/hip_runtime.h>
#include <math.h>

#define HW 65536
#define WD 256
#define HT 256

typedef short short8 __attribute__((ext_vector_type(8)));
typedef float f32x4 __attribute__((ext_vector_type(4)));
typedef __bf16 bf16x8 __attribute__((ext_vector_type(8)));

__device__ __forceinline__ short f2bf(float f) {
    union { float f; unsigned u; } v; v.f = f;
    unsigned r = (v.u + 0x7fffu + ((v.u >> 16) & 1u)) >> 16;
    return (short)r;
}

__device__ __forceinline__ float bf2f(short s) {
    union { unsigned u; float f; } v;
    v.u = ((unsigned)(unsigned short)s) << 16;
    return v.f;
}

__device__ __forceinline__ int iclamp(int v, int lo, int hi) {
    return v < lo ? lo : (v > hi ? hi : v);
}

struct Taps {
    int i00, i01, i10, i11;
    float w00, w01, w10, w11;
};

__device__ __forceinline__ Taps make_taps(float py, float px) {
    float fy0 = floorf(py), fx0 = floorf(px);
    float wy = py - fy0, wx = px - fx0;
    int y0 = (int)fy0, x0 = (int)fx0;
    int y1 = y0 + 1, x1 = x0 + 1;
    float vy0 = (y0 >= 0 && y0 <= HT - 1) ? 1.f : 0.f;
    float vy1 = (y1 >= 0 && y1 <= HT - 1) ? 1.f : 0.f;
    float vx0 = (x0 >= 0 && x0 <= WD - 1) ? 1.f : 0.f;
    float vx1 = (x1 >= 0 && x1 <= WD - 1) ? 1.f : 0.f;
    int yc0 = iclamp(y0, 0, HT - 1), yc1 = iclamp(y1, 0, HT - 1);
    int xc0 = iclamp(x0, 0, WD - 1), xc1 = iclamp(x1, 0, WD - 1);
    Taps t;
    t.i00 = yc0 * WD + xc0; t.i01 = yc0 * WD + xc1;
    t.i10 = yc1 * WD + xc0; t.i11 = yc1 * WD + xc1;
    t.w00 = (1.f - wy) * (1.f - wx) * vy0 * vx0;
    t.w01 = (1.f - wy) * wx * vy0 * vx1;
    t.w10 = wy * (1.f - wx) * vy1 * vx0;
    t.w11 = wy * wx * vy1 * vx1;
    return t;
}

// ---------------------------------------------------------------------------
// pack_x1: warp(nbr) + ref -> X1 (B,HW,128) NHWC bf16, via LDS transpose.
// ---------------------------------------------------------------------------
__global__ __launch_bounds__(256) void pack_x1_kernel(
    const float* __restrict__ nbr, const float* __restrict__ ref,
    const float* __restrict__ flow, short* __restrict__ X1)
{
    __shared__ short tile[64 * 130];
    int blk = blockIdx.x;              // b*1024 + grp
    int b = blk >> 10;
    int grp = blk & 1023;
    int px = threadIdx.x & 63;
    int qq = threadIdx.x >> 6;
    int pos = grp * 64 + px;
    int yy = pos >> 8, xx = pos & 255;

    float fx = flow[b * 2 * HW + pos];
    float fy = flow[b * 2 * HW + HW + pos];
    Taps tp = make_taps((float)yy + fy, (float)xx + fx);

    const float* nb = nbr + (size_t)b * 64 * HW;
    const float* rf = ref + (size_t)b * 64 * HW;
    #pragma unroll
    for (int j = 0; j < 16; ++j) {
        int c = qq * 16 + j;
        const float* pc = nb + c * HW;
        float v = tp.w00 * pc[tp.i00] + tp.w01 * pc[tp.i01] +
                  tp.w10 * pc[tp.i10] + tp.w11 * pc[tp.i11];
        tile[px * 130 + c] = f2bf(v);
        tile[px * 130 + 64 + c] = f2bf(rf[c * HW + pos]);
    }
    __syncthreads();

    short* xo = X1 + ((size_t)b * HW + grp * 64) * 128;
    #pragma unroll
    for (int f8 = threadIdx.x; f8 < 1024; f8 += 256) {
        int p = (f8 * 8) >> 7;
        int c = (f8 * 8) & 127;
        short8 v;
        #pragma unroll
        for (int j = 0; j < 8; ++j) v[j] = tile[p * 130 + c + j];
        *(short8*)(xo + f8 * 8) = v;
    }
}

// ---------------------------------------------------------------------------
// pack_nbr: nbr (B,64,HW) f32 -> N2 (B,8,HW,8) bf16 GROUP-MAJOR.
// A dcn tap gather for group g then reads base_g + idx*16B: consecutive
// pixels 16B apart -> ~4x fewer cache lines per gather instruction.
// ---------------------------------------------------------------------------
__global__ __launch_bounds__(256) void pack_nbr_kernel(
    const float* __restrict__ nbr, short* __restrict__ N2)
{
    __shared__ short tile[64 * 66];
    int blk = blockIdx.x;              // b*1024 + grp
    int b = blk >> 10;
    int grp = blk & 1023;
    int px = threadIdx.x & 63;
    int qq = threadIdx.x >> 6;
    int pos = grp * 64 + px;

    const float* nb = nbr + (size_t)b * 64 * HW;
    #pragma unroll
    for (int j = 0; j < 16; ++j) {
        int c = qq * 16 + j;
        tile[px * 66 + c] = f2bf(nb[c * HW + pos]);
    }
    __syncthreads();

    short* xo = N2 + (size_t)b * HW * 64;
    #pragma unroll
    for (int f8 = threadIdx.x; f8 < 512; f8 += 256) {
        int g = f8 >> 6;        // group
        int p = f8 & 63;        // pixel (lanes contiguous -> coalesced)
        short8 v;
        #pragma unroll
        for (int j = 0; j < 8; ++j) v[j] = tile[p * 66 + g * 8 + j];
        *(short8*)(xo + ((size_t)g * HW + grp * 64 + p) * 8) = v;
    }
}

// ---------------------------------------------------------------------------
// Weight repacks to MFMA B-fragment order.
// ---------------------------------------------------------------------------
__global__ __launch_bounds__(256) void repack_w1_kernel(
    const float* __restrict__ w, short* __restrict__ wr)
{
    int t = blockIdx.x * 256 + threadIdx.x;  // 73728
    int j = t & 7, q = (t >> 3) & 3, l = (t >> 5) & 15;
    int nt = (t >> 9) & 3, kc = t >> 11;
    int k = kc * 32 + q * 8 + j;
    int rs = k >> 7, c = k & 127;
    int n = nt * 16 + l;
    wr[t] = f2bf(w[(n * 128 + c) * 9 + rs]);
}

// om weights -> B-frag order for the NEW K-layout:
//   chunks 0..17: fea K = tap*64 + ch (tap = kc>>1 ... wait: k = kc*32+q*8+j,
//                 tap = k>>6, ch = k&63)
//   chunk 18:     flow K18 = 2*tap + u  (u: 0 = flow_x (orig ch 64), 1 = y)
// total 19*16*64*8 = 155648 elements.
__global__ __launch_bounds__(256) void repack_w2_kernel(
    const float* __restrict__ w, short* __restrict__ wr)
{
    int t = blockIdx.x * 256 + threadIdx.x;  // 155648
    if (t >= 155648) return;
    int j = t & 7, q = (t >> 3) & 3, l = (t >> 5) & 15;
    int nt = (t >> 9) & 15, kc = t >> 13;
    int n = nt * 16 + l;
    float v = 0.f;
    if (kc < 18) {
        int k = kc * 32 + q * 8 + j;
        int rs = k >> 6, c = k & 63;
        if (n < 216) v = w[(n * 66 + c) * 9 + rs];
    } else {
        int k18 = q * 8 + j;
        if (k18 < 18 && n < 216) {
            int tap = k18 >> 1, u = k18 & 1;
            v = w[(n * 66 + 64 + u) * 9 + tap];
        }
    }
    wr[t] = f2bf(v);
}

// dcn weights -> B-frag order: flat = (((g*3+kc)*4+nt)*64 + l15*4+q)*8 + j
__global__ __launch_bounds__(256) void repack_dcn_kernel(
    const float* __restrict__ w, short* __restrict__ wr)
{
    int t = blockIdx.x * 256 + threadIdx.x;   // 49152
    int j = t & 7, q = (t >> 3) & 3, l = (t >> 5) & 15;
    int rem = t >> 9;           // (g*3+kc)*4 + nt
    int nt = rem & 3;
    int gkc = rem >> 2;         // g*3 + kc
    int kc = gkc % 3, g = gkc / 3;
    int Kidx = kc * 32 + q * 8 + j;
    int k = Kidx >> 3, c = Kidx & 7;
    int och = nt * 16 + l;
    float v = (k < 9) ? w[(och * 64 + g * 8 + c) * 9 + k] : 0.f;
    wr[t] = f2bf(v);
}

// ---------------------------------------------------------------------------
// conv1 MFMA: X1 (NHWC bf16, 128ch) -> X2 (NHWC bf16, 64ch fea only).
// ---------------------------------------------------------------------------
#define PADC1 136
__global__ __launch_bounds__(256) void conv1_mfma_kernel(
    const short* __restrict__ X1, const float* __restrict__ bias,
    const short* __restrict__ wr, short* __restrict__ X2)
{
    __shared__ short lds[3 * 66 * PADC1];
    const int tid = threadIdx.x;
    const int w = __builtin_amdgcn_readfirstlane(tid >> 6);
    const int l15 = tid & 15;
    const int q = (tid >> 4) & 3;
    const int blk = ((blockIdx.x & 7) << 8) | (blockIdx.x >> 3);  // XCD swizzle (2048 % 8 == 0)
    const int xseg = blk & 3;
    const int yy = (blk >> 2) & 255;
    const int b = blk >> 10;
    const int x0 = xseg * 64;

    const short* xin = X1 + (size_t)b * HW * 128;
    for (int i = tid; i < 198 * 16; i += 256) {
        int c16 = i & 15;
        int pix = i >> 4;
        int r = pix / 66, xx = pix % 66;
        int gy = yy + r - 1, gx = x0 + xx - 1;
        short8 v = {0, 0, 0, 0, 0, 0, 0, 0};
        if (gy >= 0 && gy < HT && gx >= 0 && gx < WD)
            v = *(const short8*)(xin + ((size_t)((gy << 8) + gx)) * 128 + c16 * 8);
        *(short8*)(&lds[(r * 66 + xx) * PADC1 + c16 * 8]) = v;
    }
    __syncthreads();

    f32x4 acc[4] = {{0,0,0,0},{0,0,0,0},{0,0,0,0},{0,0,0,0}};
    const int bbase = l15 * 4 + q;
    const int abase = l15 * PADC1 + q * 8;

    #define LOADB1(kc_) (*(const short8*)(wr + ((size_t)(((kc_) * 4 + w) * 64 + bbase)) * 8))
    #define COMP1(kc_, bf_) { \
        int rs_ = (kc_) >> 2, cc_ = (kc_) & 3; \
        int r_ = rs_ / 3, s_ = rs_ % 3; \
        int ao_ = (r_ * 66 + s_) * PADC1 + cc_ * 32 + abase; \
        _Pragma("unroll") \
        for (int mt = 0; mt < 4; ++mt) { \
            short8 a_ = *(const short8*)(&lds[ao_ + mt * 16 * PADC1]); \
            acc[mt] = __builtin_amdgcn_mfma_f32_16x16x32_bf16(a_, bf_, acc[mt], 0, 0, 0); \
        } }

    short8 bA = LOADB1(0), bB;
    #pragma unroll 1
    for (int jj = 0; jj < 18; ++jj) {
        int kc0 = 2 * jj;
        bB = LOADB1(kc0 + 1);
        COMP1(kc0, bA);
        int kc2 = kc0 + 2; if (kc2 > 35) kc2 = 35;
        bA = LOADB1(kc2);
        COMP1(kc0 + 1, bB);
    }
    #undef LOADB1
    #undef COMP1

    float bv = bias[w * 16 + l15];
    short* xo = X2 + (size_t)b * HW * 64;
    #pragma unroll
    for (int mt = 0; mt < 4; ++mt) {
        #pragma unroll
        for (int rg = 0; rg < 4; ++rg) {
            int px = x0 + mt * 16 + q * 4 + rg;
            float v = fmaxf(acc[mt][rg] + bv, 0.f);
            xo[((size_t)((yy << 8) + px)) * 64 + w * 16 + l15] = f2bf(v);
        }
    }
}

// ---------------------------------------------------------------------------
// om MFMA: X2 (NHWC bf16, 64ch) + flow halo -> omraw (B,216,HW) fp32.
// K restructured 27 -> 19 chunks: 18 fea chunks (9 taps x 64ch) + 1 flow
// chunk (A18[64px][18] built from the flow halo during staging). The 30
// zero-pad channels of the old 96-ch layout are gone (-30% MFMA).
// ---------------------------------------------------------------------------
#define PADX 72
__global__ __launch_bounds__(256) void om_mfma_kernel(
    const short* __restrict__ X2, const float* __restrict__ flow,
    const short* __restrict__ wr, const float* __restrict__ bias,
    float* __restrict__ omraw)
{
    __shared__ __align__(16) char ldsraw[34816];
    short* ldsA = (short*)ldsraw;                 // [3*66][PADX] fea halo
    short* A18  = (short*)(ldsraw + 28512);       // [64 px][40] flow K-chunk
    float* ldsT = (float*)ldsraw;                 // epilogue alias [128][67]

    const int tid = threadIdx.x;
    const int w = __builtin_amdgcn_readfirstlane(tid >> 6);
    const int l15 = tid & 15;
    const int q = (tid >> 4) & 3;
    const int blk = ((blockIdx.x & 7) << 8) | (blockIdx.x >> 3);  // XCD swizzle
    const int xseg = blk & 3;
    const int yy = (blk >> 2) & 255;
    const int b = blk >> 10;
    const int x0 = xseg * 64;

    // stage fea halo (64 ch / px)
    const short* xin = X2 + (size_t)b * HW * 64;
    for (int i = tid; i < 198 * 8; i += 256) {
        int c8 = i & 7;
        int pix = i >> 3;
        int r = pix / 66, xx = pix % 66;
        int gy = yy + r - 1, gx = x0 + xx - 1;
        short8 v = {0, 0, 0, 0, 0, 0, 0, 0};
        if (gy >= 0 && gy < HT && gx >= 0 && gx < WD)
            v = *(const short8*)(xin + ((size_t)((gy << 8) + gx)) * 64 + c8 * 8);
        *(short8*)(&ldsA[(r * 66 + xx) * PADX + c8 * 8]) = v;
    }
    // stage flow A-chunk: A18[p][k18], k18 = 2*tap + u; pad cols 18..39 zero
    for (int i = tid; i < 64 * 40; i += 256) {
        int p = i / 40, kk = i - p * 40;
        short v = 0;
        if (kk < 18) {
            int tap = kk >> 1, u = kk & 1;
            int gy = yy + tap / 3 - 1, gx = x0 + p + tap % 3 - 1;
            if (gy >= 0 && gy < HT && gx >= 0 && gx < WD)
                v = f2bf(flow[(size_t)(b * 2 + u) * HW + (gy << 8) + gx]);
        }
        A18[p * 40 + kk] = v;
    }
    __syncthreads();

    f32x4 acc[4][4];
    #pragma unroll
    for (int i = 0; i < 4; ++i)
        #pragma unroll
        for (int mt = 0; mt < 4; ++mt) acc[i][mt] = (f32x4){0,0,0,0};

    const int bbase = l15 * 4 + q;
    const int abase = l15 * PADX + q * 8;

    #define LOADB2(dst_, kc_) { \
        _Pragma("unroll") \
        for (int i = 0; i < 4; ++i) \
            dst_[i] = *(const short8*)(wr + ((size_t)(((kc_) * 16 + w * 4 + i) * 64 + bbase)) * 8); }
    #define COMP2(kc_, bf_) { \
        int rs_ = (kc_) >> 1, half_ = (kc_) & 1; \
        int r_ = rs_ / 3, s_ = rs_ % 3; \
        int ao_ = (r_ * 66 + s_) * PADX + half_ * 32 + abase; \
        short8 a_[4]; \
        _Pragma("unroll") \
        for (int mt = 0; mt < 4; ++mt) \
            a_[mt] = *(const short8*)(&ldsA[ao_ + mt * 16 * PADX]); \
        _Pragma("unroll") \
        for (int i = 0; i < 4; ++i) \
            _Pragma("unroll") \
            for (int mt = 0; mt < 4; ++mt) \
                acc[i][mt] = __builtin_amdgcn_mfma_f32_16x16x32_bf16(a_[mt], bf_[i], acc[i][mt], 0, 0, 0); }

    short8 bA[4], bB[4];
    LOADB2(bA, 0);
    #pragma unroll 1
    for (int jj = 0; jj < 9; ++jj) {
        int kc0 = 2 * jj;
        LOADB2(bB, kc0 + 1);
        COMP2(kc0, bA);
        LOADB2(bA, kc0 + 2);     // jj==8 -> loads chunk 18 (flow B-frags)
        COMP2(kc0 + 1, bB);
    }
    // flow chunk (kc 18): A from A18
    #pragma unroll
    for (int mt = 0; mt < 4; ++mt) {
        short8 a_ = *(const short8*)(&A18[(mt * 16 + l15) * 40 + q * 8]);
        #pragma unroll
        for (int i = 0; i < 4; ++i)
            acc[i][mt] = __builtin_amdgcn_mfma_f32_16x16x32_bf16(a_, bA[i], acc[i][mt], 0, 0, 0);
    }
    #undef LOADB2
    #undef COMP2

    const int LT = 67;
    #pragma unroll 1
    for (int pass = 0; pass < 2; ++pass) {
        __syncthreads();
        if ((w >> 1) == pass) {
            int wl = w & 1;
            #pragma unroll
            for (int i = 0; i < 4; ++i) {
                int chl = (wl * 4 + i) * 16 + l15;
                #pragma unroll
                for (int mt = 0; mt < 4; ++mt)
                    #pragma unroll
                    for (int rg = 0; rg < 4; ++rg)
                        ldsT[chl * LT + mt * 16 + q * 4 + rg] = acc[i][mt][rg];
            }
        }
        __syncthreads();
        int chbase = pass * 128;
        for (int f = tid; f < 128 * 64; f += 256) {
            int chl = f >> 6, px = f & 63;
            int ch = chbase + chl;
            if (ch < 216) {
                float v = ldsT[chl * LT + px] + bias[ch];
                omraw[((size_t)b * 216 + ch) * HW + (yy << 8) + x0 + px] = v;
            }
        }
    }
}

// ---------------------------------------------------------------------------
// dcn MFMA — round-5 pipelined structure; N2 now GROUP-MAJOR (B,8,HW,8):
// gathers for group g read base_g + idx*16B -> consecutive pixels 16B apart,
// ~4x fewer cache lines per gather wave-instruction.
// ---------------------------------------------------------------------------
__global__ __launch_bounds__(256) void dcn_mfma_kernel(
    const float* __restrict__ raw,    // (B,216,HW)
    const float* __restrict__ flow,   // (B,2,HW)
    const short* __restrict__ N2,     // (B,8,HW,8) bf16 group-major
    const short* __restrict__ wrd,    // B-frag order, 49152
    const float* __restrict__ bias,   // 64
    float* __restrict__ out)          // (B,64,HW)
{
    __shared__ __align__(16) char ldsraw[26624];
    short* bufA = (short*)ldsraw;                 // [64 px][104]
    short* bufB = (short*)(ldsraw + 13312);       // [64 px][104]
    float* ldsT = (float*)ldsraw;                 // [64 och][65] epilogue alias

    const int tid = threadIdx.x;
    const int w = __builtin_amdgcn_readfirstlane(tid >> 6);
    const int l15 = tid & 15;
    const int q = (tid >> 4) & 3;
    const int qq = tid >> 6;
    const int px = tid & 63;

    const int blk = ((blockIdx.x & 7) << 8) | (blockIdx.x >> 3);  // XCD swizzle
    const int b = blk >> 10;
    const int grp = blk & 1023;
    const int pos0 = grp * 64;
    const int pos = pos0 + px;
    const int yy = pos >> 8, xx = pos & 255;

    const float* rawb = raw + (size_t)b * 216 * HW + pos;
    const float fx = flow[b * 2 * HW + pos];
    const float fy = flow[b * 2 * HW + HW + pos];
    const short* n2b = N2 + (size_t)b * HW * 64;   // base of this batch's 8 group planes

    // zero pad K-slots (k = 9..11) in BOTH buffers once
    {
        short8 z = {0, 0, 0, 0, 0, 0, 0, 0};
        #pragma unroll
        for (int it = 0; it < 3; ++it) {
            int k = qq + 4 * it;
            if (k >= 9) {
                *(short8*)(&bufA[px * 104 + k * 8]) = z;
                *(short8*)(&bufB[px * 104 + k * 8]) = z;
            }
        }
    }

    f32x4 acc[4] = {{0,0,0,0},{0,0,0,0},{0,0,0,0},{0,0,0,0}};

    // raw offset/mask loads for g=0
    float rdy[3], rdx[3], rm[3];
    #pragma unroll
    for (int it = 0; it < 3; ++it) {
        int k = qq + 4 * it;
        rdy[it] = 0.f; rdx[it] = 0.f; rm[it] = 0.f;
        if (k < 9) {
            rdy[it] = rawb[(size_t)(2 * k) * HW];
            rdx[it] = rawb[(size_t)(2 * k + 1) * HW];
            rm[it]  = rawb[(size_t)(144 + k) * HW];
        }
    }

    // ---- prologue: fill group 0 into bufA ----
    {
        const short* nbg = n2b;                    // group 0 plane
        float w00[3], w01[3], w10[3], w11[3];
        short8 a00[3], a01[3], a10[3], a11[3];
        #pragma unroll
        for (int it = 0; it < 3; ++it) {
            int k = qq + 4 * it;
            if (k < 9) {
                float dy = rdy[it] + fy, dx = rdx[it] + fx;
                float m = 1.f / (1.f + __expf(-rm[it]));
                Taps tp = make_taps((float)(yy - 1 + k / 3) + dy,
                                    (float)(xx - 1 + k % 3) + dx);
                w00[it] = tp.w00 * m; w01[it] = tp.w01 * m;
                w10[it] = tp.w10 * m; w11[it] = tp.w11 * m;
                a00[it] = *(const short8*)(nbg + (size_t)tp.i00 * 8);
                a01[it] = *(const short8*)(nbg + (size_t)tp.i01 * 8);
                a10[it] = *(const short8*)(nbg + (size_t)tp.i10 * 8);
                a11[it] = *(const short8*)(nbg + (size_t)tp.i11 * 8);
            }
        }
        // prefetch raw g=1 (after the gathers: stays in flight through blend)
        #pragma unroll
        for (int it = 0; it < 3; ++it) {
            int k = qq + 4 * it;
            if (k < 9) {
                rdy[it] = rawb[(size_t)(18 + 2 * k) * HW];
                rdx[it] = rawb[(size_t)(18 + 2 * k + 1) * HW];
                rm[it]  = rawb[(size_t)(144 + 9 + k) * HW];
            }
        }
        #pragma unroll
        for (int it = 0; it < 3; ++it) {
            int k = qq + 4 * it;
            if (k < 9) {
                union { bf16x8 bv; short8 s; } u;
                #pragma unroll
                for (int c = 0; c < 8; ++c) {
                    float s = w00[it] * bf2f(a00[it][c]) + w01[it] * bf2f(a01[it][c]) +
                              w10[it] * bf2f(a10[it][c]) + w11[it] * bf2f(a11[it][c]);
                    u.bv[c] = (__bf16)s;
                }
                *(short8*)(&bufA[px * 104 + k * 8]) = u.s;
            }
        }
    }
    __syncthreads();

    // ---- pipelined main loop: one barrier per group ----
    #pragma unroll 1
    for (int g = 0; g < 8; ++g) {
        short* cur = (g & 1) ? bufB : bufA;
        short* nxt = (g & 1) ? bufA : bufB;

        // issue gathers for group g+1 (12 loads in flight across the MFMAs)
        float w00[3], w01[3], w10[3], w11[3];
        short8 a00[3], a01[3], a10[3], a11[3];
        if (g < 7) {
            const short* nbg = n2b + (size_t)(g + 1) * HW * 8;
            #pragma unroll
            for (int it = 0; it < 3; ++it) {
                int k = qq + 4 * it;
                if (k < 9) {
                    float dy = rdy[it] + fy, dx = rdx[it] + fx;
                    float m = 1.f / (1.f + __expf(-rm[it]));
                    Taps tp = make_taps((float)(yy - 1 + k / 3) + dy,
                                        (float)(xx - 1 + k % 3) + dx);
                    w00[it] = tp.w00 * m; w01[it] = tp.w01 * m;
                    w10[it] = tp.w10 * m; w11[it] = tp.w11 * m;
                    a00[it] = *(const short8*)(nbg + (size_t)tp.i00 * 8);
                    a01[it] = *(const short8*)(nbg + (size_t)tp.i01 * 8);
                    a10[it] = *(const short8*)(nbg + (size_t)tp.i10 * 8);
                    a11[it] = *(const short8*)(nbg + (size_t)tp.i11 * 8);
                }
            }
            // prefetch raw for g+2 (after gathers: not drained by their wait)
            if (g < 6) {
                #pragma unroll
                for (int it = 0; it < 3; ++it) {
                    int k = qq + 4 * it;
                    if (k < 9) {
                        rdy[it] = rawb[(size_t)((g + 2) * 18 + 2 * k) * HW];
                        rdx[it] = rawb[(size_t)((g + 2) * 18 + 2 * k + 1) * HW];
                        rm[it]  = rawb[(size_t)(144 + (g + 2) * 9 + k) * HW];
                    }
                }
            }
        }

        // MFMA group g from cur (hides the gather latency)
        #pragma unroll
        for (int kc = 0; kc < 3; ++kc) {
            short8 bfrag = *(const short8*)(wrd +
                ((size_t)(((g * 3 + kc) * 4 + w) * 64 + l15 * 4 + q)) * 8);
            #pragma unroll
            for (int mt = 0; mt < 4; ++mt) {
                short8 a = *(const short8*)(&cur[(mt * 16 + l15) * 104 + kc * 32 + q * 8]);
                acc[mt] = __builtin_amdgcn_mfma_f32_16x16x32_bf16(a, bfrag, acc[mt], 0, 0, 0);
            }
        }

        // blend g+1 -> nxt
        if (g < 7) {
            #pragma unroll
            for (int it = 0; it < 3; ++it) {
                int k = qq + 4 * it;
                if (k < 9) {
                    union { bf16x8 bv; short8 s; } u;
                    #pragma unroll
                    for (int c = 0; c < 8; ++c) {
                        float s = w00[it] * bf2f(a00[it][c]) + w01[it] * bf2f(a01[it][c]) +
                                  w10[it] * bf2f(a10[it][c]) + w11[it] * bf2f(a11[it][c]);
                        u.bv[c] = (__bf16)s;
                    }
                    *(short8*)(&nxt[px * 104 + k * 8]) = u.s;
                }
            }
        }
        __syncthreads();
    }

    // epilogue: LDS transpose -> coalesced NCHW stores (+bias)
    #pragma unroll
    for (int mt = 0; mt < 4; ++mt)
        #pragma unroll
        for (int rg = 0; rg < 4; ++rg)
            ldsT[(w * 16 + l15) * 65 + mt * 16 + q * 4 + rg] = acc[mt][rg];
    __syncthreads();
    float* ob = out + (size_t)b * 64 * HW + pos0;
    for (int f = tid; f < 4096; f += 256) {
        int och = f >> 6, p2 = f & 63;
        ob[(size_t)och * HW + p2] = ldsT[och * 65 + p2] + bias[och];
    }
}

// ---------------------------------------------------------------------------
extern "C" void kernel_launch(void* const* d_in, const int* in_sizes, int n_in,
                              void* d_out, int out_size, void* d_ws, size_t ws_size,
                              hipStream_t stream)
{
    const float* nbr  = (const float*)d_in[0];
    const float* ref  = (const float*)d_in[1];
    const float* flow = (const float*)d_in[2];
    const float* c1w  = (const float*)d_in[3];
    const float* c1b  = (const float*)d_in[4];
    const float* omw  = (const float*)d_in[5];
    const float* omb  = (const float*)d_in[6];
    const float* dw   = (const float*)d_in[7];
    const float* db   = (const float*)d_in[8];
    float* out = (float*)d_out;

    char* wsb = (char*)d_ws;
    short* X1    = (short*)(wsb);                  // 33,554,432 B
    short* X2    = (short*)(wsb + 33554432);       // 16,777,216 B used (64ch)
    float* omraw = (float*)(wsb + 58720256);       // 113,246,208 B
    short* wr1   = (short*)(wsb + 171966464);      // 147,456 B
    short* wr2   = (short*)(wsb + 172113920);      // 311,296 B used
    short* wrd   = (short*)(wsb + 172556288);      // 98,304 B
    // N2 aliases X1: X1 is dead after conv1_mfma; stream serializes kernels.
    short* N2    = X1;                             // 16,777,216 B

    repack_w1_kernel<<<288, 256, 0, stream>>>(c1w, wr1);
    repack_w2_kernel<<<608, 256, 0, stream>>>(omw, wr2);
    repack_dcn_kernel<<<192, 256, 0, stream>>>(dw, wrd);
    pack_x1_kernel<<<2048, 256, 0, stream>>>(nbr, ref, flow, X1);
    conv1_mfma_kernel<<<2048, 256, 0, stream>>>(X1, c1b, wr1, X2);
    pack_nbr_kernel<<<2048, 256, 0, stream>>>(nbr, N2);   // overwrites X1
    om_mfma_kernel<<<2048, 256, 0, stream>>>(X2, flow, wr2, omb, omraw);
    dcn_mfma_kernel<<<2048, 256, 0, stream>>>(omraw, flow, N2, wrd, db, out);
}

// Round 7
// 361.832 us; speedup vs baseline: 1.2540x; 1.0142x over previous
//
#include <hip/hip_runtime.h>
#include <math.h>

#define HW 65536
#define WD 256
#define HT 256

typedef short short8 __attribute__((ext_vector_type(8)));
typedef float f32x4 __attribute__((ext_vector_type(4)));
typedef __bf16 bf16x8 __attribute__((ext_vector_type(8)));

__device__ __forceinline__ short f2bf(float f) {
    union { float f; unsigned u; } v; v.f = f;
    unsigned r = (v.u + 0x7fffu + ((v.u >> 16) & 1u)) >> 16;
    return (short)r;
}

__device__ __forceinline__ float bf2f(short s) {
    union { unsigned u; float f; } v;
    v.u = ((unsigned)(unsigned short)s) << 16;
    return v.f;
}

__device__ __forceinline__ int iclamp(int v, int lo, int hi) {
    return v < lo ? lo : (v > hi ? hi : v);
}

struct Taps {
    int i00, i01, i10, i11;
    float w00, w01, w10, w11;
};

__device__ __forceinline__ Taps make_taps(float py, float px) {
    float fy0 = floorf(py), fx0 = floorf(px);
    float wy = py - fy0, wx = px - fx0;
    int y0 = (int)fy0, x0 = (int)fx0;
    int y1 = y0 + 1, x1 = x0 + 1;
    float vy0 = (y0 >= 0 && y0 <= HT - 1) ? 1.f : 0.f;
    float vy1 = (y1 >= 0 && y1 <= HT - 1) ? 1.f : 0.f;
    float vx0 = (x0 >= 0 && x0 <= WD - 1) ? 1.f : 0.f;
    float vx1 = (x1 >= 0 && x1 <= WD - 1) ? 1.f : 0.f;
    int yc0 = iclamp(y0, 0, HT - 1), yc1 = iclamp(y1, 0, HT - 1);
    int xc0 = iclamp(x0, 0, WD - 1), xc1 = iclamp(x1, 0, WD - 1);
    Taps t;
    t.i00 = yc0 * WD + xc0; t.i01 = yc0 * WD + xc1;
    t.i10 = yc1 * WD + xc0; t.i11 = yc1 * WD + xc1;
    t.w00 = (1.f - wy) * (1.f - wx) * vy0 * vx0;
    t.w01 = (1.f - wy) * wx * vy0 * vx1;
    t.w10 = wy * (1.f - wx) * vy1 * vx0;
    t.w11 = wy * wx * vy1 * vx1;
    return t;
}

// ---------------------------------------------------------------------------
// pack_x1: warp(nbr) + ref -> X1 (B,HW,128) NHWC bf16, via LDS transpose.
// ---------------------------------------------------------------------------
__global__ __launch_bounds__(256) void pack_x1_kernel(
    const float* __restrict__ nbr, const float* __restrict__ ref,
    const float* __restrict__ flow, short* __restrict__ X1)
{
    __shared__ short tile[64 * 130];
    int blk = blockIdx.x;              // b*1024 + grp
    int b = blk >> 10;
    int grp = blk & 1023;
    int px = threadIdx.x & 63;
    int qq = threadIdx.x >> 6;
    int pos = grp * 64 + px;
    int yy = pos >> 8, xx = pos & 255;

    float fx = flow[b * 2 * HW + pos];
    float fy = flow[b * 2 * HW + HW + pos];
    Taps tp = make_taps((float)yy + fy, (float)xx + fx);

    const float* nb = nbr + (size_t)b * 64 * HW;
    const float* rf = ref + (size_t)b * 64 * HW;
    #pragma unroll
    for (int j = 0; j < 16; ++j) {
        int c = qq * 16 + j;
        const float* pc = nb + c * HW;
        float v = tp.w00 * pc[tp.i00] + tp.w01 * pc[tp.i01] +
                  tp.w10 * pc[tp.i10] + tp.w11 * pc[tp.i11];
        tile[px * 130 + c] = f2bf(v);
        tile[px * 130 + 64 + c] = f2bf(rf[c * HW + pos]);
    }
    __syncthreads();

    short* xo = X1 + ((size_t)b * HW + grp * 64) * 128;
    #pragma unroll
    for (int f8 = threadIdx.x; f8 < 1024; f8 += 256) {
        int p = (f8 * 8) >> 7;
        int c = (f8 * 8) & 127;
        short8 v;
        #pragma unroll
        for (int j = 0; j < 8; ++j) v[j] = tile[p * 130 + c + j];
        *(short8*)(xo + f8 * 8) = v;
    }
}

// ---------------------------------------------------------------------------
// pack_nbr: nbr (B,64,HW) f32 -> N2 (B,8,HW,8) bf16 GROUP-MAJOR.
// ---------------------------------------------------------------------------
__global__ __launch_bounds__(256) void pack_nbr_kernel(
    const float* __restrict__ nbr, short* __restrict__ N2)
{
    __shared__ short tile[64 * 66];
    int blk = blockIdx.x;              // b*1024 + grp
    int b = blk >> 10;
    int grp = blk & 1023;
    int px = threadIdx.x & 63;
    int qq = threadIdx.x >> 6;
    int pos = grp * 64 + px;

    const float* nb = nbr + (size_t)b * 64 * HW;
    #pragma unroll
    for (int j = 0; j < 16; ++j) {
        int c = qq * 16 + j;
        tile[px * 66 + c] = f2bf(nb[c * HW + pos]);
    }
    __syncthreads();

    short* xo = N2 + (size_t)b * HW * 64;
    #pragma unroll
    for (int f8 = threadIdx.x; f8 < 512; f8 += 256) {
        int g = f8 >> 6;        // group
        int p = f8 & 63;        // pixel (lanes contiguous -> coalesced)
        short8 v;
        #pragma unroll
        for (int j = 0; j < 8; ++j) v[j] = tile[p * 66 + g * 8 + j];
        *(short8*)(xo + ((size_t)g * HW + grp * 64 + p) * 8) = v;
    }
}

// ---------------------------------------------------------------------------
// Weight repacks to MFMA B-fragment order.
// ---------------------------------------------------------------------------
__global__ __launch_bounds__(256) void repack_w1_kernel(
    const float* __restrict__ w, short* __restrict__ wr)
{
    int t = blockIdx.x * 256 + threadIdx.x;  // 73728
    int j = t & 7, q = (t >> 3) & 3, l = (t >> 5) & 15;
    int nt = (t >> 9) & 3, kc = t >> 11;
    int k = kc * 32 + q * 8 + j;
    int rs = k >> 7, c = k & 127;
    int n = nt * 16 + l;
    wr[t] = f2bf(w[(n * 128 + c) * 9 + rs]);
}

// om weights -> B-frag order:
//   chunks 0..17: fea K (tap = k>>6, ch = k&63); chunk 18: flow (2*tap+u)
__global__ __launch_bounds__(256) void repack_w2_kernel(
    const float* __restrict__ w, short* __restrict__ wr)
{
    int t = blockIdx.x * 256 + threadIdx.x;  // 155648
    if (t >= 155648) return;
    int j = t & 7, q = (t >> 3) & 3, l = (t >> 5) & 15;
    int nt = (t >> 9) & 15, kc = t >> 13;
    int n = nt * 16 + l;
    float v = 0.f;
    if (kc < 18) {
        int k = kc * 32 + q * 8 + j;
        int rs = k >> 6, c = k & 63;
        if (n < 216) v = w[(n * 66 + c) * 9 + rs];
    } else {
        int k18 = q * 8 + j;
        if (k18 < 18 && n < 216) {
            int tap = k18 >> 1, u = k18 & 1;
            v = w[(n * 66 + 64 + u) * 9 + tap];
        }
    }
    wr[t] = f2bf(v);
}

// dcn weights -> B-frag order: flat = (((g*3+kc)*4+nt)*64 + l15*4+q)*8 + j
__global__ __launch_bounds__(256) void repack_dcn_kernel(
    const float* __restrict__ w, short* __restrict__ wr)
{
    int t = blockIdx.x * 256 + threadIdx.x;   // 49152
    int j = t & 7, q = (t >> 3) & 3, l = (t >> 5) & 15;
    int rem = t >> 9;           // (g*3+kc)*4 + nt
    int nt = rem & 3;
    int gkc = rem >> 2;         // g*3 + kc
    int kc = gkc % 3, g = gkc / 3;
    int Kidx = kc * 32 + q * 8 + j;
    int k = Kidx >> 3, c = Kidx & 7;
    int och = nt * 16 + l;
    float v = (k < 9) ? w[(och * 64 + g * 8 + c) * 9 + k] : 0.f;
    wr[t] = f2bf(v);
}

// ---------------------------------------------------------------------------
// conv1 MFMA: X1 (NHWC bf16, 128ch) -> X2 (NHWC bf16, 64ch fea only).
// PADC1 136->128 + XOR swizzle (col16 ^= row&7): bank-conflict-free ds_read
// and LDS 53.9->50.7 KB (2 -> 3 blocks/CU).
// ---------------------------------------------------------------------------
#define PADC1 128
__global__ __launch_bounds__(256) void conv1_mfma_kernel(
    const short* __restrict__ X1, const float* __restrict__ bias,
    const short* __restrict__ wr, short* __restrict__ X2)
{
    __shared__ short lds[198 * PADC1];
    const int tid = threadIdx.x;
    const int w = __builtin_amdgcn_readfirstlane(tid >> 6);
    const int l15 = tid & 15;
    const int q = (tid >> 4) & 3;
    const int blk = ((blockIdx.x & 7) << 8) | (blockIdx.x >> 3);  // XCD swizzle (2048 % 8 == 0)
    const int xseg = blk & 3;
    const int yy = (blk >> 2) & 255;
    const int b = blk >> 10;
    const int x0 = xseg * 64;

    const short* xin = X1 + (size_t)b * HW * 128;
    for (int i = tid; i < 198 * 16; i += 256) {
        int c16 = i & 15;
        int pix = i >> 4;
        int r = pix / 66, xx = pix % 66;
        int gy = yy + r - 1, gx = x0 + xx - 1;
        short8 v = {0, 0, 0, 0, 0, 0, 0, 0};
        if (gy >= 0 && gy < HT && gx >= 0 && gx < WD)
            v = *(const short8*)(xin + ((size_t)((gy << 8) + gx)) * 128 + c16 * 8);
        *(short8*)(&lds[pix * PADC1 + (c16 ^ (pix & 7)) * 8]) = v;
    }
    __syncthreads();

    f32x4 acc[4] = {{0,0,0,0},{0,0,0,0},{0,0,0,0},{0,0,0,0}};
    const int bbase = l15 * 4 + q;

    #define LOADB1(kc_) (*(const short8*)(wr + ((size_t)(((kc_) * 4 + w) * 64 + bbase)) * 8))
    #define COMP1(kc_, bf_) { \
        int rs_ = (kc_) >> 2, cc_ = (kc_) & 3; \
        int r_ = rs_ / 3, s_ = rs_ % 3; \
        int rowb_ = r_ * 66 + s_ + l15; \
        _Pragma("unroll") \
        for (int mt = 0; mt < 4; ++mt) { \
            int row_ = rowb_ + mt * 16; \
            int col16_ = (cc_ * 4 + q) ^ (row_ & 7); \
            short8 a_ = *(const short8*)(&lds[row_ * PADC1 + col16_ * 8]); \
            acc[mt] = __builtin_amdgcn_mfma_f32_16x16x32_bf16(a_, bf_, acc[mt], 0, 0, 0); \
        } }

    short8 bA = LOADB1(0), bB;
    #pragma unroll 1
    for (int jj = 0; jj < 18; ++jj) {
        int kc0 = 2 * jj;
        bB = LOADB1(kc0 + 1);
        COMP1(kc0, bA);
        int kc2 = kc0 + 2; if (kc2 > 35) kc2 = 35;
        bA = LOADB1(kc2);
        COMP1(kc0 + 1, bB);
    }
    #undef LOADB1
    #undef COMP1

    float bv = bias[w * 16 + l15];
    short* xo = X2 + (size_t)b * HW * 64;
    #pragma unroll
    for (int mt = 0; mt < 4; ++mt) {
        #pragma unroll
        for (int rg = 0; rg < 4; ++rg) {
            int px = x0 + mt * 16 + q * 4 + rg;
            float v = fmaxf(acc[mt][rg] + bv, 0.f);
            xo[((size_t)((yy << 8) + px)) * 64 + w * 16 + l15] = f2bf(v);
        }
    }
}

// ---------------------------------------------------------------------------
// om MFMA: X2 (NHWC bf16, 64ch) + flow halo -> omraw (B,216,HW) fp32.
// This round: PADX 72->64 + XOR swizzle (bank-conflict-free A reads) and
// 4-pass epilogue (64x65 transpose buffer): LDS 34.8 -> 30.5 KB -> 5
// blocks/CU (+25% TLP to hide the per-chunk B-frag L2 latency).
// ---------------------------------------------------------------------------
#define PADX 64
__global__ __launch_bounds__(256) void om_mfma_kernel(
    const short* __restrict__ X2, const float* __restrict__ flow,
    const short* __restrict__ wr, const float* __restrict__ bias,
    float* __restrict__ omraw)
{
    __shared__ __align__(16) char ldsraw[30464];
    short* ldsA = (short*)ldsraw;                 // [198][64] fea halo, swizzled
    short* A18  = (short*)(ldsraw + 25344);       // [64 px][40] flow K-chunk
    float* ldsT = (float*)ldsraw;                 // epilogue alias [64][65]

    const int tid = threadIdx.x;
    const int w = __builtin_amdgcn_readfirstlane(tid >> 6);
    const int l15 = tid & 15;
    const int q = (tid >> 4) & 3;
    const int blk = ((blockIdx.x & 7) << 8) | (blockIdx.x >> 3);  // XCD swizzle
    const int xseg = blk & 3;
    const int yy = (blk >> 2) & 255;
    const int b = blk >> 10;
    const int x0 = xseg * 64;

    // stage fea halo (64 ch / px), XOR-swizzled 16B blocks within each row
    const short* xin = X2 + (size_t)b * HW * 64;
    for (int i = tid; i < 198 * 8; i += 256) {
        int c8 = i & 7;
        int pix = i >> 3;
        int r = pix / 66, xx = pix % 66;
        int gy = yy + r - 1, gx = x0 + xx - 1;
        short8 v = {0, 0, 0, 0, 0, 0, 0, 0};
        if (gy >= 0 && gy < HT && gx >= 0 && gx < WD)
            v = *(const short8*)(xin + ((size_t)((gy << 8) + gx)) * 64 + c8 * 8);
        *(short8*)(&ldsA[pix * PADX + (c8 ^ (pix & 7)) * 8]) = v;
    }
    // stage flow A-chunk: A18[p][k18], k18 = 2*tap + u; pad cols 18..39 zero
    for (int i = tid; i < 64 * 40; i += 256) {
        int p = i / 40, kk = i - p * 40;
        short v = 0;
        if (kk < 18) {
            int tap = kk >> 1, u = kk & 1;
            int gy = yy + tap / 3 - 1, gx = x0 + p + tap % 3 - 1;
            if (gy >= 0 && gy < HT && gx >= 0 && gx < WD)
                v = f2bf(flow[(size_t)(b * 2 + u) * HW + (gy << 8) + gx]);
        }
        A18[p * 40 + kk] = v;
    }
    __syncthreads();

    f32x4 acc[4][4];
    #pragma unroll
    for (int i = 0; i < 4; ++i)
        #pragma unroll
        for (int mt = 0; mt < 4; ++mt) acc[i][mt] = (f32x4){0,0,0,0};

    const int bbase = l15 * 4 + q;

    #define LOADB2(dst_, kc_) { \
        _Pragma("unroll") \
        for (int i = 0; i < 4; ++i) \
            dst_[i] = *(const short8*)(wr + ((size_t)(((kc_) * 16 + w * 4 + i) * 64 + bbase)) * 8); }
    #define COMP2(kc_, bf_) { \
        int rs_ = (kc_) >> 1, half_ = (kc_) & 1; \
        int r_ = rs_ / 3, s_ = rs_ % 3; \
        int rowb_ = r_ * 66 + s_ + l15; \
        short8 a_[4]; \
        _Pragma("unroll") \
        for (int mt = 0; mt < 4; ++mt) { \
            int row_ = rowb_ + mt * 16; \
            int col16_ = (half_ * 4 + q) ^ (row_ & 7); \
            a_[mt] = *(const short8*)(&ldsA[row_ * PADX + col16_ * 8]); \
        } \
        _Pragma("unroll") \
        for (int i = 0; i < 4; ++i) \
            _Pragma("unroll") \
            for (int mt = 0; mt < 4; ++mt) \
                acc[i][mt] = __builtin_amdgcn_mfma_f32_16x16x32_bf16(a_[mt], bf_[i], acc[i][mt], 0, 0, 0); }

    short8 bA[4], bB[4];
    LOADB2(bA, 0);
    #pragma unroll 1
    for (int jj = 0; jj < 9; ++jj) {
        int kc0 = 2 * jj;
        LOADB2(bB, kc0 + 1);
        COMP2(kc0, bA);
        LOADB2(bA, kc0 + 2);     // jj==8 -> loads chunk 18 (flow B-frags)
        COMP2(kc0 + 1, bB);
    }
    // flow chunk (kc 18): A from A18
    #pragma unroll
    for (int mt = 0; mt < 4; ++mt) {
        short8 a_ = *(const short8*)(&A18[(mt * 16 + l15) * 40 + q * 8]);
        #pragma unroll
        for (int i = 0; i < 4; ++i)
            acc[i][mt] = __builtin_amdgcn_mfma_f32_16x16x32_bf16(a_, bA[i], acc[i][mt], 0, 0, 0);
    }
    #undef LOADB2
    #undef COMP2

    // epilogue: 4 passes, wave p transposes its own 64 och (16.6 KB buffer)
    const int LT = 65;
    #pragma unroll 1
    for (int pass = 0; pass < 4; ++pass) {
        __syncthreads();
        if (w == pass) {
            #pragma unroll
            for (int i = 0; i < 4; ++i) {
                int chl = i * 16 + l15;
                #pragma unroll
                for (int mt = 0; mt < 4; ++mt)
                    #pragma unroll
                    for (int rg = 0; rg < 4; ++rg)
                        ldsT[chl * LT + mt * 16 + q * 4 + rg] = acc[i][mt][rg];
            }
        }
        __syncthreads();
        int chbase = pass * 64;
        for (int f = tid; f < 64 * 64; f += 256) {
            int chl = f >> 6, px = f & 63;
            int ch = chbase + chl;
            if (ch < 216) {
                float v = ldsT[chl * LT + px] + bias[ch];
                omraw[((size_t)b * 216 + ch) * HW + (yy << 8) + x0 + px] = v;
            }
        }
    }
}

// ---------------------------------------------------------------------------
// dcn MFMA — pipelined structure; N2 GROUP-MAJOR (B,8,HW,8). Unchanged.
// ---------------------------------------------------------------------------
__global__ __launch_bounds__(256) void dcn_mfma_kernel(
    const float* __restrict__ raw,    // (B,216,HW)
    const float* __restrict__ flow,   // (B,2,HW)
    const short* __restrict__ N2,     // (B,8,HW,8) bf16 group-major
    const short* __restrict__ wrd,    // B-frag order, 49152
    const float* __restrict__ bias,   // 64
    float* __restrict__ out)          // (B,64,HW)
{
    __shared__ __align__(16) char ldsraw[26624];
    short* bufA = (short*)ldsraw;                 // [64 px][104]
    short* bufB = (short*)(ldsraw + 13312);       // [64 px][104]
    float* ldsT = (float*)ldsraw;                 // [64 och][65] epilogue alias

    const int tid = threadIdx.x;
    const int w = __builtin_amdgcn_readfirstlane(tid >> 6);
    const int l15 = tid & 15;
    const int q = (tid >> 4) & 3;
    const int qq = tid >> 6;
    const int px = tid & 63;

    const int blk = ((blockIdx.x & 7) << 8) | (blockIdx.x >> 3);  // XCD swizzle
    const int b = blk >> 10;
    const int grp = blk & 1023;
    const int pos0 = grp * 64;
    const int pos = pos0 + px;
    const int yy = pos >> 8, xx = pos & 255;

    const float* rawb = raw + (size_t)b * 216 * HW + pos;
    const float fx = flow[b * 2 * HW + pos];
    const float fy = flow[b * 2 * HW + HW + pos];
    const short* n2b = N2 + (size_t)b * HW * 64;   // base of this batch's 8 group planes

    // zero pad K-slots (k = 9..11) in BOTH buffers once
    {
        short8 z = {0, 0, 0, 0, 0, 0, 0, 0};
        #pragma unroll
        for (int it = 0; it < 3; ++it) {
            int k = qq + 4 * it;
            if (k >= 9) {
                *(short8*)(&bufA[px * 104 + k * 8]) = z;
                *(short8*)(&bufB[px * 104 + k * 8]) = z;
            }
        }
    }

    f32x4 acc[4] = {{0,0,0,0},{0,0,0,0},{0,0,0,0},{0,0,0,0}};

    // raw offset/mask loads for g=0
    float rdy[3], rdx[3], rm[3];
    #pragma unroll
    for (int it = 0; it < 3; ++it) {
        int k = qq + 4 * it;
        rdy[it] = 0.f; rdx[it] = 0.f; rm[it] = 0.f;
        if (k < 9) {
            rdy[it] = rawb[(size_t)(2 * k) * HW];
            rdx[it] = rawb[(size_t)(2 * k + 1) * HW];
            rm[it]  = rawb[(size_t)(144 + k) * HW];
        }
    }

    // ---- prologue: fill group 0 into bufA ----
    {
        const short* nbg = n2b;                    // group 0 plane
        float w00[3], w01[3], w10[3], w11[3];
        short8 a00[3], a01[3], a10[3], a11[3];
        #pragma unroll
        for (int it = 0; it < 3; ++it) {
            int k = qq + 4 * it;
            if (k < 9) {
                float dy = rdy[it] + fy, dx = rdx[it] + fx;
                float m = 1.f / (1.f + __expf(-rm[it]));
                Taps tp = make_taps((float)(yy - 1 + k / 3) + dy,
                                    (float)(xx - 1 + k % 3) + dx);
                w00[it] = tp.w00 * m; w01[it] = tp.w01 * m;
                w10[it] = tp.w10 * m; w11[it] = tp.w11 * m;
                a00[it] = *(const short8*)(nbg + (size_t)tp.i00 * 8);
                a01[it] = *(const short8*)(nbg + (size_t)tp.i01 * 8);
                a10[it] = *(const short8*)(nbg + (size_t)tp.i10 * 8);
                a11[it] = *(const short8*)(nbg + (size_t)tp.i11 * 8);
            }
        }
        // prefetch raw g=1 (after the gathers: stays in flight through blend)
        #pragma unroll
        for (int it = 0; it < 3; ++it) {
            int k = qq + 4 * it;
            if (k < 9) {
                rdy[it] = rawb[(size_t)(18 + 2 * k) * HW];
                rdx[it] = rawb[(size_t)(18 + 2 * k + 1) * HW];
                rm[it]  = rawb[(size_t)(144 + 9 + k) * HW];
            }
        }
        #pragma unroll
        for (int it = 0; it < 3; ++it) {
            int k = qq + 4 * it;
            if (k < 9) {
                union { bf16x8 bv; short8 s; } u;
                #pragma unroll
                for (int c = 0; c < 8; ++c) {
                    float s = w00[it] * bf2f(a00[it][c]) + w01[it] * bf2f(a01[it][c]) +
                              w10[it] * bf2f(a10[it][c]) + w11[it] * bf2f(a11[it][c]);
                    u.bv[c] = (__bf16)s;
                }
                *(short8*)(&bufA[px * 104 + k * 8]) = u.s;
            }
        }
    }
    __syncthreads();

    // ---- pipelined main loop: one barrier per group ----
    #pragma unroll 1
    for (int g = 0; g < 8; ++g) {
        short* cur = (g & 1) ? bufB : bufA;
        short* nxt = (g & 1) ? bufA : bufB;

        // issue gathers for group g+1 (12 loads in flight across the MFMAs)
        float w00[3], w01[3], w10[3], w11[3];
        short8 a00[3], a01[3], a10[3], a11[3];
        if (g < 7) {
            const short* nbg = n2b + (size_t)(g + 1) * HW * 8;
            #pragma unroll
            for (int it = 0; it < 3; ++it) {
                int k = qq + 4 * it;
                if (k < 9) {
                    float dy = rdy[it] + fy, dx = rdx[it] + fx;
                    float m = 1.f / (1.f + __expf(-rm[it]));
                    Taps tp = make_taps((float)(yy - 1 + k / 3) + dy,
                                        (float)(xx - 1 + k % 3) + dx);
                    w00[it] = tp.w00 * m; w01[it] = tp.w01 * m;
                    w10[it] = tp.w10 * m; w11[it] = tp.w11 * m;
                    a00[it] = *(const short8*)(nbg + (size_t)tp.i00 * 8);
                    a01[it] = *(const short8*)(nbg + (size_t)tp.i01 * 8);
                    a10[it] = *(const short8*)(nbg + (size_t)tp.i10 * 8);
                    a11[it] = *(const short8*)(nbg + (size_t)tp.i11 * 8);
                }
            }
            // prefetch raw for g+2 (after gathers: not drained by their wait)
            if (g < 6) {
                #pragma unroll
                for (int it = 0; it < 3; ++it) {
                    int k = qq + 4 * it;
                    if (k < 9) {
                        rdy[it] = rawb[(size_t)((g + 2) * 18 + 2 * k) * HW];
                        rdx[it] = rawb[(size_t)((g + 2) * 18 + 2 * k + 1) * HW];
                        rm[it]  = rawb[(size_t)(144 + (g + 2) * 9 + k) * HW];
                    }
                }
            }
        }

        // MFMA group g from cur (hides the gather latency)
        #pragma unroll
        for (int kc = 0; kc < 3; ++kc) {
            short8 bfrag = *(const short8*)(wrd +
                ((size_t)(((g * 3 + kc) * 4 + w) * 64 + l15 * 4 + q)) * 8);
            #pragma unroll
            for (int mt = 0; mt < 4; ++mt) {
                short8 a = *(const short8*)(&cur[(mt * 16 + l15) * 104 + kc * 32 + q * 8]);
                acc[mt] = __builtin_amdgcn_mfma_f32_16x16x32_bf16(a, bfrag, acc[mt], 0, 0, 0);
            }
        }

        // blend g+1 -> nxt
        if (g < 7) {
            #pragma unroll
            for (int it = 0; it < 3; ++it) {
                int k = qq + 4 * it;
                if (k < 9) {
                    union { bf16x8 bv; short8 s; } u;
                    #pragma unroll
                    for (int c = 0; c < 8; ++c) {
                        float s = w00[it] * bf2f(a00[it][c]) + w01[it] * bf2f(a01[it][c]) +
                                  w10[it] * bf2f(a10[it][c]) + w11[it] * bf2f(a11[it][c]);
                        u.bv[c] = (__bf16)s;
                    }
                    *(short8*)(&nxt[px * 104 + k * 8]) = u.s;
                }
            }
        }
        __syncthreads();
    }

    // epilogue: LDS transpose -> coalesced NCHW stores (+bias)
    #pragma unroll
    for (int mt = 0; mt < 4; ++mt)
        #pragma unroll
        for (int rg = 0; rg < 4; ++rg)
            ldsT[(w * 16 + l15) * 65 + mt * 16 + q * 4 + rg] = acc[mt][rg];
    __syncthreads();
    float* ob = out + (size_t)b * 64 * HW + pos0;
    for (int f = tid; f < 4096; f += 256) {
        int och = f >> 6, p2 = f & 63;
        ob[(size_t)och * HW + p2] = ldsT[och * 65 + p2] + bias[och];
    }
}

// ---------------------------------------------------------------------------
extern "C" void kernel_launch(void* const* d_in, const int* in_sizes, int n_in,
                              void* d_out, int out_size, void* d_ws, size_t ws_size,
                              hipStream_t stream)
{
    const float* nbr  = (const float*)d_in[0];
    const float* ref  = (const float*)d_in[1];
    const float* flow = (const float*)d_in[2];
    const float* c1w  = (const float*)d_in[3];
    const float* c1b  = (const float*)d_in[4];
    const float* omw  = (const float*)d_in[5];
    const float* omb  = (const float*)d_in[6];
    const float* dw   = (const float*)d_in[7];
    const float* db   = (const float*)d_in[8];
    float* out = (float*)d_out;

    char* wsb = (char*)d_ws;
    short* X1    = (short*)(wsb);                  // 33,554,432 B
    short* X2    = (short*)(wsb + 33554432);       // 16,777,216 B used (64ch)
    float* omraw = (float*)(wsb + 58720256);       // 113,246,208 B
    short* wr1   = (short*)(wsb + 171966464);      // 147,456 B
    short* wr2   = (short*)(wsb + 172113920);      // 311,296 B used
    short* wrd   = (short*)(wsb + 172556288);      // 98,304 B
    // N2 aliases X1: X1 is dead after conv1_mfma; stream serializes kernels.
    short* N2    = X1;                             // 16,777,216 B

    repack_w1_kernel<<<288, 256, 0, stream>>>(c1w, wr1);
    repack_w2_kernel<<<608, 256, 0, stream>>>(omw, wr2);
    repack_dcn_kernel<<<192, 256, 0, stream>>>(dw, wrd);
    pack_x1_kernel<<<2048, 256, 0, stream>>>(nbr, ref, flow, X1);
    conv1_mfma_kernel<<<2048, 256, 0, stream>>>(X1, c1b, wr1, X2);
    pack_nbr_kernel<<<2048, 256, 0, stream>>>(nbr, N2);   // overwrites X1
    om_mfma_kernel<<<2048, 256, 0, stream>>>(X2, flow, wr2, omb, omraw);
    dcn_mfma_kernel<<<2048, 256, 0, stream>>>(omraw, flow, N2, wrd, db, out);
}

// Round 8
// 322.130 us; speedup vs baseline: 1.4086x; 1.1232x over previous
//
#include <hip/hip_runtime.h>
#include <math.h>

#define HW 65536
#define WD 256
#define HT 256

typedef short short8 __attribute__((ext_vector_type(8)));
typedef float f32x4 __attribute__((ext_vector_type(4)));
typedef __bf16 bf16x8 __attribute__((ext_vector_type(8)));

__device__ __forceinline__ short f2bf(float f) {
    union { float f; unsigned u; } v; v.f = f;
    unsigned r = (v.u + 0x7fffu + ((v.u >> 16) & 1u)) >> 16;
    return (short)r;
}

__device__ __forceinline__ float bf2f(short s) {
    union { unsigned u; float f; } v;
    v.u = ((unsigned)(unsigned short)s) << 16;
    return v.f;
}

__device__ __forceinline__ int iclamp(int v, int lo, int hi) {
    return v < lo ? lo : (v > hi ? hi : v);
}

struct Taps {
    int i00, i01, i10, i11;
    float w00, w01, w10, w11;
};

__device__ __forceinline__ Taps make_taps(float py, float px) {
    float fy0 = floorf(py), fx0 = floorf(px);
    float wy = py - fy0, wx = px - fx0;
    int y0 = (int)fy0, x0 = (int)fx0;
    int y1 = y0 + 1, x1 = x0 + 1;
    float vy0 = (y0 >= 0 && y0 <= HT - 1) ? 1.f : 0.f;
    float vy1 = (y1 >= 0 && y1 <= HT - 1) ? 1.f : 0.f;
    float vx0 = (x0 >= 0 && x0 <= WD - 1) ? 1.f : 0.f;
    float vx1 = (x1 >= 0 && x1 <= WD - 1) ? 1.f : 0.f;
    int yc0 = iclamp(y0, 0, HT - 1), yc1 = iclamp(y1, 0, HT - 1);
    int xc0 = iclamp(x0, 0, WD - 1), xc1 = iclamp(x1, 0, WD - 1);
    Taps t;
    t.i00 = yc0 * WD + xc0; t.i01 = yc0 * WD + xc1;
    t.i10 = yc1 * WD + xc0; t.i11 = yc1 * WD + xc1;
    t.w00 = (1.f - wy) * (1.f - wx) * vy0 * vx0;
    t.w01 = (1.f - wy) * wx * vy0 * vx1;
    t.w10 = wy * (1.f - wx) * vy1 * vx0;
    t.w11 = wy * wx * vy1 * vx1;
    return t;
}

// ---------------------------------------------------------------------------
// pack_x1: warp(nbr) + ref -> X1 (B,HW,128) NHWC bf16, via LDS transpose.
// ---------------------------------------------------------------------------
__global__ __launch_bounds__(256) void pack_x1_kernel(
    const float* __restrict__ nbr, const float* __restrict__ ref,
    const float* __restrict__ flow, short* __restrict__ X1)
{
    __shared__ short tile[64 * 130];
    int blk = blockIdx.x;              // b*1024 + grp
    int b = blk >> 10;
    int grp = blk & 1023;
    int px = threadIdx.x & 63;
    int qq = threadIdx.x >> 6;
    int pos = grp * 64 + px;
    int yy = pos >> 8, xx = pos & 255;

    float fx = flow[b * 2 * HW + pos];
    float fy = flow[b * 2 * HW + HW + pos];
    Taps tp = make_taps((float)yy + fy, (float)xx + fx);

    const float* nb = nbr + (size_t)b * 64 * HW;
    const float* rf = ref + (size_t)b * 64 * HW;
    #pragma unroll
    for (int j = 0; j < 16; ++j) {
        int c = qq * 16 + j;
        const float* pc = nb + c * HW;
        float v = tp.w00 * pc[tp.i00] + tp.w01 * pc[tp.i01] +
                  tp.w10 * pc[tp.i10] + tp.w11 * pc[tp.i11];
        tile[px * 130 + c] = f2bf(v);
        tile[px * 130 + 64 + c] = f2bf(rf[c * HW + pos]);
    }
    __syncthreads();

    short* xo = X1 + ((size_t)b * HW + grp * 64) * 128;
    #pragma unroll
    for (int f8 = threadIdx.x; f8 < 1024; f8 += 256) {
        int p = (f8 * 8) >> 7;
        int c = (f8 * 8) & 127;
        short8 v;
        #pragma unroll
        for (int j = 0; j < 8; ++j) v[j] = tile[p * 130 + c + j];
        *(short8*)(xo + f8 * 8) = v;
    }
}

// ---------------------------------------------------------------------------
// pack_nbr: nbr (B,64,HW) f32 -> N2 (B,8,HW,8) bf16 GROUP-MAJOR.
// ---------------------------------------------------------------------------
__global__ __launch_bounds__(256) void pack_nbr_kernel(
    const float* __restrict__ nbr, short* __restrict__ N2)
{
    __shared__ short tile[64 * 66];
    int blk = blockIdx.x;              // b*1024 + grp
    int b = blk >> 10;
    int grp = blk & 1023;
    int px = threadIdx.x & 63;
    int qq = threadIdx.x >> 6;
    int pos = grp * 64 + px;

    const float* nb = nbr + (size_t)b * 64 * HW;
    #pragma unroll
    for (int j = 0; j < 16; ++j) {
        int c = qq * 16 + j;
        tile[px * 66 + c] = f2bf(nb[c * HW + pos]);
    }
    __syncthreads();

    short* xo = N2 + (size_t)b * HW * 64;
    #pragma unroll
    for (int f8 = threadIdx.x; f8 < 512; f8 += 256) {
        int g = f8 >> 6;        // group
        int p = f8 & 63;        // pixel (lanes contiguous -> coalesced)
        short8 v;
        #pragma unroll
        for (int j = 0; j < 8; ++j) v[j] = tile[p * 66 + g * 8 + j];
        *(short8*)(xo + ((size_t)g * HW + grp * 64 + p) * 8) = v;
    }
}

// ---------------------------------------------------------------------------
// Weight repacks to MFMA B-fragment order.
// ---------------------------------------------------------------------------
__global__ __launch_bounds__(256) void repack_w1_kernel(
    const float* __restrict__ w, short* __restrict__ wr)
{
    int t = blockIdx.x * 256 + threadIdx.x;  // 73728
    int j = t & 7, q = (t >> 3) & 3, l = (t >> 5) & 15;
    int nt = (t >> 9) & 3, kc = t >> 11;
    int k = kc * 32 + q * 8 + j;
    int rs = k >> 7, c = k & 127;
    int n = nt * 16 + l;
    wr[t] = f2bf(w[(n * 128 + c) * 9 + rs]);
}

// om weights -> B-frag order:
//   chunks 0..17: fea K (tap = k>>6, ch = k&63); chunk 18: flow (2*tap+u)
__global__ __launch_bounds__(256) void repack_w2_kernel(
    const float* __restrict__ w, short* __restrict__ wr)
{
    int t = blockIdx.x * 256 + threadIdx.x;  // 155648
    if (t >= 155648) return;
    int j = t & 7, q = (t >> 3) & 3, l = (t >> 5) & 15;
    int nt = (t >> 9) & 15, kc = t >> 13;
    int n = nt * 16 + l;
    float v = 0.f;
    if (kc < 18) {
        int k = kc * 32 + q * 8 + j;
        int rs = k >> 6, c = k & 63;
        if (n < 216) v = w[(n * 66 + c) * 9 + rs];
    } else {
        int k18 = q * 8 + j;
        if (k18 < 18 && n < 216) {
            int tap = k18 >> 1, u = k18 & 1;
            v = w[(n * 66 + 64 + u) * 9 + tap];
        }
    }
    wr[t] = f2bf(v);
}

// dcn weights -> B-frag order: flat = (((g*3+kc)*4+nt)*64 + l15*4+q)*8 + j
__global__ __launch_bounds__(256) void repack_dcn_kernel(
    const float* __restrict__ w, short* __restrict__ wr)
{
    int t = blockIdx.x * 256 + threadIdx.x;   // 49152
    int j = t & 7, q = (t >> 3) & 3, l = (t >> 5) & 15;
    int rem = t >> 9;           // (g*3+kc)*4 + nt
    int nt = rem & 3;
    int gkc = rem >> 2;         // g*3 + kc
    int kc = gkc % 3, g = gkc / 3;
    int Kidx = kc * 32 + q * 8 + j;
    int k = Kidx >> 3, c = Kidx & 7;
    int och = nt * 16 + l;
    float v = (k < 9) ? w[(och * 64 + g * 8 + c) * 9 + k] : 0.f;
    wr[t] = f2bf(v);
}

// ---------------------------------------------------------------------------
// conv1 MFMA: X1 (NHWC bf16, 128ch) -> X2 (NHWC bf16, 64ch fea only).
// ---------------------------------------------------------------------------
#define PADC1 128
__global__ __launch_bounds__(256) void conv1_mfma_kernel(
    const short* __restrict__ X1, const float* __restrict__ bias,
    const short* __restrict__ wr, short* __restrict__ X2)
{
    __shared__ short lds[198 * PADC1];
    const int tid = threadIdx.x;
    const int w = __builtin_amdgcn_readfirstlane(tid >> 6);
    const int l15 = tid & 15;
    const int q = (tid >> 4) & 3;
    const int blk = ((blockIdx.x & 7) << 8) | (blockIdx.x >> 3);  // XCD swizzle (2048 % 8 == 0)
    const int xseg = blk & 3;
    const int yy = (blk >> 2) & 255;
    const int b = blk >> 10;
    const int x0 = xseg * 64;

    const short* xin = X1 + (size_t)b * HW * 128;
    for (int i = tid; i < 198 * 16; i += 256) {
        int c16 = i & 15;
        int pix = i >> 4;
        int r = pix / 66, xx = pix % 66;
        int gy = yy + r - 1, gx = x0 + xx - 1;
        short8 v = {0, 0, 0, 0, 0, 0, 0, 0};
        if (gy >= 0 && gy < HT && gx >= 0 && gx < WD)
            v = *(const short8*)(xin + ((size_t)((gy << 8) + gx)) * 128 + c16 * 8);
        *(short8*)(&lds[pix * PADC1 + (c16 ^ (pix & 7)) * 8]) = v;
    }
    __syncthreads();

    f32x4 acc[4] = {{0,0,0,0},{0,0,0,0},{0,0,0,0},{0,0,0,0}};
    const int bbase = l15 * 4 + q;

    #define LOADB1(kc_) (*(const short8*)(wr + ((size_t)(((kc_) * 4 + w) * 64 + bbase)) * 8))
    #define COMP1(kc_, bf_) { \
        int rs_ = (kc_) >> 2, cc_ = (kc_) & 3; \
        int r_ = rs_ / 3, s_ = rs_ % 3; \
        int rowb_ = r_ * 66 + s_ + l15; \
        _Pragma("unroll") \
        for (int mt = 0; mt < 4; ++mt) { \
            int row_ = rowb_ + mt * 16; \
            int col16_ = (cc_ * 4 + q) ^ (row_ & 7); \
            short8 a_ = *(const short8*)(&lds[row_ * PADC1 + col16_ * 8]); \
            acc[mt] = __builtin_amdgcn_mfma_f32_16x16x32_bf16(a_, bf_, acc[mt], 0, 0, 0); \
        } }

    short8 bA = LOADB1(0), bB;
    #pragma unroll 1
    for (int jj = 0; jj < 18; ++jj) {
        int kc0 = 2 * jj;
        bB = LOADB1(kc0 + 1);
        COMP1(kc0, bA);
        int kc2 = kc0 + 2; if (kc2 > 35) kc2 = 35;
        bA = LOADB1(kc2);
        COMP1(kc0 + 1, bB);
    }
    #undef LOADB1
    #undef COMP1

    float bv = bias[w * 16 + l15];
    short* xo = X2 + (size_t)b * HW * 64;
    #pragma unroll
    for (int mt = 0; mt < 4; ++mt) {
        #pragma unroll
        for (int rg = 0; rg < 4; ++rg) {
            int px = x0 + mt * 16 + q * 4 + rg;
            float v = fmaxf(acc[mt][rg] + bv, 0.f);
            xo[((size_t)((yy << 8) + px)) * 64 + w * 16 + l15] = f2bf(v);
        }
    }
}

// ---------------------------------------------------------------------------
// om MFMA: X2 (NHWC bf16, 64ch) + flow halo -> omraw (B,216,HW) fp32.
// This round: M=128 px per block (grid 1024). Per chunk each wave issues
// 32 MFMAs (was 16) -> ping-ponged B-frag L2 loads fully covered by same-
// wave MFMA issue; B-frag traffic halves. Epilogue: 2 passes (2 waves
// active each), f32x4 stores (was 4 passes / 1 wave / scalar stores).
// acc[4][8] (~190 VGPR) at 2 waves/SIMD: trade TLP for 2x per-wave ILP.
// ---------------------------------------------------------------------------
#define PADX2 64
__global__ __launch_bounds__(256, 2) void om_mfma_kernel(
    const short* __restrict__ X2, const float* __restrict__ flow,
    const short* __restrict__ wr, const float* __restrict__ bias,
    float* __restrict__ omraw)
{
    __shared__ __align__(16) char ldsraw[67584];
    short* ldsA = (short*)ldsraw;                  // [390][64] swizzled fea halo
    short* A18  = (short*)(ldsraw + 49920);        // [128][34] flow K-chunk
    float* ldsT = (float*)ldsraw;                  // [128][132] epilogue alias

    const int tid = threadIdx.x;
    const int w = __builtin_amdgcn_readfirstlane(tid >> 6);
    const int l15 = tid & 15;
    const int q = (tid >> 4) & 3;
    const int blk = ((blockIdx.x & 7) << 7) | (blockIdx.x >> 3);  // XCD swizzle (1024)
    const int xseg = blk & 1;
    const int yy = (blk >> 1) & 255;
    const int b = blk >> 9;
    const int x0 = xseg * 128;

    // stage fea halo: 3 rows x 130 px x 64 ch, XOR-swizzled 16B blocks
    const short* xin = X2 + (size_t)b * HW * 64;
    #pragma unroll
    for (int r = 0; r < 3; ++r) {
        int gy = yy + r - 1;
        for (int i = tid; i < 130 * 8; i += 256) {
            int xx = i >> 3, c8 = i & 7;
            int gx = x0 + xx - 1;
            short8 v = {0, 0, 0, 0, 0, 0, 0, 0};
            if (gy >= 0 && gy < HT && gx >= 0 && gx < WD)
                v = *(const short8*)(xin + ((size_t)((gy << 8) + gx)) * 64 + c8 * 8);
            int pix = r * 130 + xx;
            *(short8*)(&ldsA[pix * PADX2 + (c8 ^ (pix & 7)) * 8]) = v;
        }
    }
    // stage flow A-chunk [128 px][34]: cols 0..17 = flow halo, 18..31 zero
    for (int i = tid; i < 128 * 32; i += 256) {
        int p = i >> 5, kk = i & 31;
        short v = 0;
        if (kk < 18) {
            int tap = kk >> 1, u = kk & 1;
            int gy = yy + tap / 3 - 1, gx = x0 + p + tap % 3 - 1;
            if (gy >= 0 && gy < HT && gx >= 0 && gx < WD)
                v = f2bf(flow[(size_t)(b * 2 + u) * HW + (gy << 8) + gx]);
        }
        A18[p * 34 + kk] = v;
    }
    __syncthreads();

    f32x4 acc[4][8];
    #pragma unroll
    for (int i = 0; i < 4; ++i)
        #pragma unroll
        for (int mt = 0; mt < 8; ++mt) acc[i][mt] = (f32x4){0, 0, 0, 0};

    const int bbase = l15 * 4 + q;

    #define LOADB2(dst_, kc_) { \
        _Pragma("unroll") \
        for (int i = 0; i < 4; ++i) \
            dst_[i] = *(const short8*)(wr + ((size_t)(((kc_) * 16 + w * 4 + i) * 64 + bbase)) * 8); }
    #define COMP2(kc_, bf_) { \
        int rs_ = (kc_) >> 1, half_ = (kc_) & 1; \
        int r_ = rs_ / 3, s_ = rs_ % 3; \
        int rowb_ = r_ * 130 + s_ + l15; \
        _Pragma("unroll") \
        for (int mt = 0; mt < 8; ++mt) { \
            int row_ = rowb_ + mt * 16; \
            int col16_ = (half_ * 4 + q) ^ (row_ & 7); \
            short8 a_ = *(const short8*)(&ldsA[row_ * PADX2 + col16_ * 8]); \
            _Pragma("unroll") \
            for (int i = 0; i < 4; ++i) \
                acc[i][mt] = __builtin_amdgcn_mfma_f32_16x16x32_bf16(a_, bf_[i], acc[i][mt], 0, 0, 0); \
        } }

    short8 bA[4], bB[4];
    LOADB2(bA, 0);
    #pragma unroll 1
    for (int jj = 0; jj < 9; ++jj) {
        int kc0 = 2 * jj;
        LOADB2(bB, kc0 + 1);
        COMP2(kc0, bA);
        LOADB2(bA, kc0 + 2);     // jj==8 -> loads chunk 18 (flow B-frags)
        COMP2(kc0 + 1, bB);
    }
    // flow chunk (kc 18): A from A18
    #pragma unroll
    for (int mt = 0; mt < 8; ++mt) {
        short8 a_ = *(const short8*)(&A18[(mt * 16 + l15) * 34 + q * 8]);
        #pragma unroll
        for (int i = 0; i < 4; ++i)
            acc[i][mt] = __builtin_amdgcn_mfma_f32_16x16x32_bf16(a_, bA[i], acc[i][mt], 0, 0, 0);
    }
    #undef LOADB2
    #undef COMP2

    // epilogue: 2 passes; waves {0,1} write och 0..127, {2,3} och 128..215.
    // Stores are f32x4 (16B aligned: stride-132 rows, 128-px segments).
    #pragma unroll 1
    for (int pass = 0; pass < 2; ++pass) {
        __syncthreads();
        if ((w >> 1) == pass) {
            int ochl_base = (w & 1) * 64;
            #pragma unroll
            for (int i = 0; i < 4; ++i) {
                int ochl = ochl_base + i * 16 + l15;
                #pragma unroll
                for (int mt = 0; mt < 8; ++mt)
                    #pragma unroll
                    for (int rg = 0; rg < 4; ++rg)
                        ldsT[ochl * 132 + mt * 16 + q * 4 + rg] = acc[i][mt][rg];
            }
        }
        __syncthreads();
        for (int f = tid; f < 128 * 32; f += 256) {
            int chl = f >> 5, p16 = (f & 31) * 4;
            int ch = pass * 128 + chl;
            if (ch < 216) {
                f32x4 v = *(const f32x4*)(&ldsT[chl * 132 + p16]);
                float bv = bias[ch];
                v[0] += bv; v[1] += bv; v[2] += bv; v[3] += bv;
                *(f32x4*)(&omraw[((size_t)b * 216 + ch) * HW + (yy << 8) + x0 + p16]) = v;
            }
        }
    }
}

// ---------------------------------------------------------------------------
// dcn MFMA — pipelined structure; N2 GROUP-MAJOR (B,8,HW,8). Unchanged.
// ---------------------------------------------------------------------------
__global__ __launch_bounds__(256) void dcn_mfma_kernel(
    const float* __restrict__ raw,    // (B,216,HW)
    const float* __restrict__ flow,   // (B,2,HW)
    const short* __restrict__ N2,     // (B,8,HW,8) bf16 group-major
    const short* __restrict__ wrd,    // B-frag order, 49152
    const float* __restrict__ bias,   // 64
    float* __restrict__ out)          // (B,64,HW)
{
    __shared__ __align__(16) char ldsraw[26624];
    short* bufA = (short*)ldsraw;                 // [64 px][104]
    short* bufB = (short*)(ldsraw + 13312);       // [64 px][104]
    float* ldsT = (float*)ldsraw;                 // [64 och][65] epilogue alias

    const int tid = threadIdx.x;
    const int w = __builtin_amdgcn_readfirstlane(tid >> 6);
    const int l15 = tid & 15;
    const int q = (tid >> 4) & 3;
    const int qq = tid >> 6;
    const int px = tid & 63;

    const int blk = ((blockIdx.x & 7) << 8) | (blockIdx.x >> 3);  // XCD swizzle
    const int b = blk >> 10;
    const int grp = blk & 1023;
    const int pos0 = grp * 64;
    const int pos = pos0 + px;
    const int yy = pos >> 8, xx = pos & 255;

    const float* rawb = raw + (size_t)b * 216 * HW + pos;
    const float fx = flow[b * 2 * HW + pos];
    const float fy = flow[b * 2 * HW + HW + pos];
    const short* n2b = N2 + (size_t)b * HW * 64;   // base of this batch's 8 group planes

    // zero pad K-slots (k = 9..11) in BOTH buffers once
    {
        short8 z = {0, 0, 0, 0, 0, 0, 0, 0};
        #pragma unroll
        for (int it = 0; it < 3; ++it) {
            int k = qq + 4 * it;
            if (k >= 9) {
                *(short8*)(&bufA[px * 104 + k * 8]) = z;
                *(short8*)(&bufB[px * 104 + k * 8]) = z;
            }
        }
    }

    f32x4 acc[4] = {{0,0,0,0},{0,0,0,0},{0,0,0,0},{0,0,0,0}};

    // raw offset/mask loads for g=0
    float rdy[3], rdx[3], rm[3];
    #pragma unroll
    for (int it = 0; it < 3; ++it) {
        int k = qq + 4 * it;
        rdy[it] = 0.f; rdx[it] = 0.f; rm[it] = 0.f;
        if (k < 9) {
            rdy[it] = rawb[(size_t)(2 * k) * HW];
            rdx[it] = rawb[(size_t)(2 * k + 1) * HW];
            rm[it]  = rawb[(size_t)(144 + k) * HW];
        }
    }

    // ---- prologue: fill group 0 into bufA ----
    {
        const short* nbg = n2b;                    // group 0 plane
        float w00[3], w01[3], w10[3], w11[3];
        short8 a00[3], a01[3], a10[3], a11[3];
        #pragma unroll
        for (int it = 0; it < 3; ++it) {
            int k = qq + 4 * it;
            if (k < 9) {
                float dy = rdy[it] + fy, dx = rdx[it] + fx;
                float m = 1.f / (1.f + __expf(-rm[it]));
                Taps tp = make_taps((float)(yy - 1 + k / 3) + dy,
                                    (float)(xx - 1 + k % 3) + dx);
                w00[it] = tp.w00 * m; w01[it] = tp.w01 * m;
                w10[it] = tp.w10 * m; w11[it] = tp.w11 * m;
                a00[it] = *(const short8*)(nbg + (size_t)tp.i00 * 8);
                a01[it] = *(const short8*)(nbg + (size_t)tp.i01 * 8);
                a10[it] = *(const short8*)(nbg + (size_t)tp.i10 * 8);
                a11[it] = *(const short8*)(nbg + (size_t)tp.i11 * 8);
            }
        }
        // prefetch raw g=1 (after the gathers: stays in flight through blend)
        #pragma unroll
        for (int it = 0; it < 3; ++it) {
            int k = qq + 4 * it;
            if (k < 9) {
                rdy[it] = rawb[(size_t)(18 + 2 * k) * HW];
                rdx[it] = rawb[(size_t)(18 + 2 * k + 1) * HW];
                rm[it]  = rawb[(size_t)(144 + 9 + k) * HW];
            }
        }
        #pragma unroll
        for (int it = 0; it < 3; ++it) {
            int k = qq + 4 * it;
            if (k < 9) {
                union { bf16x8 bv; short8 s; } u;
                #pragma unroll
                for (int c = 0; c < 8; ++c) {
                    float s = w00[it] * bf2f(a00[it][c]) + w01[it] * bf2f(a01[it][c]) +
                              w10[it] * bf2f(a10[it][c]) + w11[it] * bf2f(a11[it][c]);
                    u.bv[c] = (__bf16)s;
                }
                *(short8*)(&bufA[px * 104 + k * 8]) = u.s;
            }
        }
    }
    __syncthreads();

    // ---- pipelined main loop: one barrier per group ----
    #pragma unroll 1
    for (int g = 0; g < 8; ++g) {
        short* cur = (g & 1) ? bufB : bufA;
        short* nxt = (g & 1) ? bufA : bufB;

        // issue gathers for group g+1 (12 loads in flight across the MFMAs)
        float w00[3], w01[3], w10[3], w11[3];
        short8 a00[3], a01[3], a10[3], a11[3];
        if (g < 7) {
            const short* nbg = n2b + (size_t)(g + 1) * HW * 8;
            #pragma unroll
            for (int it = 0; it < 3; ++it) {
                int k = qq + 4 * it;
                if (k < 9) {
                    float dy = rdy[it] + fy, dx = rdx[it] + fx;
                    float m = 1.f / (1.f + __expf(-rm[it]));
                    Taps tp = make_taps((float)(yy - 1 + k / 3) + dy,
                                        (float)(xx - 1 + k % 3) + dx);
                    w00[it] = tp.w00 * m; w01[it] = tp.w01 * m;
                    w10[it] = tp.w10 * m; w11[it] = tp.w11 * m;
                    a00[it] = *(const short8*)(nbg + (size_t)tp.i00 * 8);
                    a01[it] = *(const short8*)(nbg + (size_t)tp.i01 * 8);
                    a10[it] = *(const short8*)(nbg + (size_t)tp.i10 * 8);
                    a11[it] = *(const short8*)(nbg + (size_t)tp.i11 * 8);
                }
            }
            // prefetch raw for g+2 (after gathers: not drained by their wait)
            if (g < 6) {
                #pragma unroll
                for (int it = 0; it < 3; ++it) {
                    int k = qq + 4 * it;
                    if (k < 9) {
                        rdy[it] = rawb[(size_t)((g + 2) * 18 + 2 * k) * HW];
                        rdx[it] = rawb[(size_t)((g + 2) * 18 + 2 * k + 1) * HW];
                        rm[it]  = rawb[(size_t)(144 + (g + 2) * 9 + k) * HW];
                    }
                }
            }
        }

        // MFMA group g from cur (hides the gather latency)
        #pragma unroll
        for (int kc = 0; kc < 3; ++kc) {
            short8 bfrag = *(const short8*)(wrd +
                ((size_t)(((g * 3 + kc) * 4 + w) * 64 + l15 * 4 + q)) * 8);
            #pragma unroll
            for (int mt = 0; mt < 4; ++mt) {
                short8 a = *(const short8*)(&cur[(mt * 16 + l15) * 104 + kc * 32 + q * 8]);
                acc[mt] = __builtin_amdgcn_mfma_f32_16x16x32_bf16(a, bfrag, acc[mt], 0, 0, 0);
            }
        }

        // blend g+1 -> nxt
        if (g < 7) {
            #pragma unroll
            for (int it = 0; it < 3; ++it) {
                int k = qq + 4 * it;
                if (k < 9) {
                    union { bf16x8 bv; short8 s; } u;
                    #pragma unroll
                    for (int c = 0; c < 8; ++c) {
                        float s = w00[it] * bf2f(a00[it][c]) + w01[it] * bf2f(a01[it][c]) +
                                  w10[it] * bf2f(a10[it][c]) + w11[it] * bf2f(a11[it][c]);
                        u.bv[c] = (__bf16)s;
                    }
                    *(short8*)(&nxt[px * 104 + k * 8]) = u.s;
                }
            }
        }
        __syncthreads();
    }

    // epilogue: LDS transpose -> coalesced NCHW stores (+bias)
    #pragma unroll
    for (int mt = 0; mt < 4; ++mt)
        #pragma unroll
        for (int rg = 0; rg < 4; ++rg)
            ldsT[(w * 16 + l15) * 65 + mt * 16 + q * 4 + rg] = acc[mt][rg];
    __syncthreads();
    float* ob = out + (size_t)b * 64 * HW + pos0;
    for (int f = tid; f < 4096; f += 256) {
        int och = f >> 6, p2 = f & 63;
        ob[(size_t)och * HW + p2] = ldsT[och * 65 + p2] + bias[och];
    }
}

// ---------------------------------------------------------------------------
extern "C" void kernel_launch(void* const* d_in, const int* in_sizes, int n_in,
                              void* d_out, int out_size, void* d_ws, size_t ws_size,
                              hipStream_t stream)
{
    const float* nbr  = (const float*)d_in[0];
    const float* ref  = (const float*)d_in[1];
    const float* flow = (const float*)d_in[2];
    const float* c1w  = (const float*)d_in[3];
    const float* c1b  = (const float*)d_in[4];
    const float* omw  = (const float*)d_in[5];
    const float* omb  = (const float*)d_in[6];
    const float* dw   = (const float*)d_in[7];
    const float* db   = (const float*)d_in[8];
    float* out = (float*)d_out;

    char* wsb = (char*)d_ws;
    short* X1    = (short*)(wsb);                  // 33,554,432 B
    short* X2    = (short*)(wsb + 33554432);       // 16,777,216 B used (64ch)
    float* omraw = (float*)(wsb + 58720256);       // 113,246,208 B
    short* wr1   = (short*)(wsb + 171966464);      // 147,456 B
    short* wr2   = (short*)(wsb + 172113920);      // 311,296 B used
    short* wrd   = (short*)(wsb + 172556288);      // 98,304 B
    // N2 aliases X1: X1 is dead after conv1_mfma; stream serializes kernels.
    short* N2    = X1;                             // 16,777,216 B

    repack_w1_kernel<<<288, 256, 0, stream>>>(c1w, wr1);
    repack_w2_kernel<<<608, 256, 0, stream>>>(omw, wr2);
    repack_dcn_kernel<<<192, 256, 0, stream>>>(dw, wrd);
    pack_x1_kernel<<<2048, 256, 0, stream>>>(nbr, ref, flow, X1);
    conv1_mfma_kernel<<<2048, 256, 0, stream>>>(X1, c1b, wr1, X2);
    pack_nbr_kernel<<<2048, 256, 0, stream>>>(nbr, N2);   // overwrites X1
    om_mfma_kernel<<<1024, 256, 0, stream>>>(X2, flow, wr2, omb, omraw);
    dcn_mfma_kernel<<<2048, 256, 0, stream>>>(omraw, flow, N2, wrd, db, out);
}